// Round 7
// baseline (1964.538 us; speedup 1.0000x reference)
//
#include <hip/hip_runtime.h>
#include <math.h>

#define NN 50000
#define NE 800000
#define NGRAPH 100
#define NPG 500
#define NB_SCAN 196
#define NCHUNK 5
#define NPC 100                        // nodes per moments chunk
#define CHAIN_ELEMS ((size_t)NN * 64)
#define CH4 ((size_t)NN * 16)          // float4 (or half4) elements per plane
#define GRID_PROP (NN / 4)             // 4 nodes (waves) per 256-thr block

typedef long long ll;
typedef _Float16 h4_t __attribute__((ext_vector_type(4)));
typedef _Float16 h8_t __attribute__((ext_vector_type(8)));

__device__ __forceinline__ void unpack(ll v, int& r, float& w) {
    r = (int)(v & 0xffffffffLL);
    w = __int_as_float((int)(v >> 32));
}

__device__ __forceinline__ float4 f4fma(float w, float4 v, float4 a) {
    a.x += w * v.x; a.y += w * v.y; a.z += w * v.z; a.w += w * v.w;
    return a;
}

__device__ __forceinline__ float4 h4f4(h4_t h) {
    return make_float4((float)h.x, (float)h.y, (float)h.z, (float)h.w);
}

__device__ __forceinline__ h4_t f4h4(float4 v) {
    h4_t h;
    h.x = (_Float16)v.x; h.y = (_Float16)v.y;
    h.z = (_Float16)v.z; h.w = (_Float16)v.w;
    return h;
}

// ---------------- setup kernels ----------------

__global__ void k_deg(const int* __restrict__ col, int* __restrict__ degi) {
    int e = blockIdx.x * blockDim.x + threadIdx.x;
    if (e < NE) atomicAdd(&degi[col[e]], 1);
}

__global__ void k_dh(const int* __restrict__ degi, float* __restrict__ dh) {
    int i = blockIdx.x * blockDim.x + threadIdx.x;
    if (i < NN) {
        int d = degi[i];
        dh[i] = d > 0 ? (float)(1.0 / sqrt((double)d)) : 0.0f;
    }
}

__global__ void k_bsum(const int* __restrict__ cnt, int* __restrict__ bsum) {
    __shared__ int sh[256];
    int i = blockIdx.x * 256 + threadIdx.x;
    sh[threadIdx.x] = (i < NN) ? cnt[i] : 0;
    __syncthreads();
    for (int s = 128; s > 0; s >>= 1) {
        if (threadIdx.x < s) sh[threadIdx.x] += sh[threadIdx.x + s];
        __syncthreads();
    }
    if (threadIdx.x == 0) bsum[blockIdx.x] = sh[0];
}

__global__ void k_bscan(const int* __restrict__ bsum, int* __restrict__ boff) {
    __shared__ int sh[2][256];
    int v = (threadIdx.x < NB_SCAN) ? bsum[threadIdx.x] : 0;
    int cur = 0;
    sh[0][threadIdx.x] = v;
    __syncthreads();
    for (int s = 1; s < 256; s <<= 1) {
        int val = sh[cur][threadIdx.x];
        if ((int)threadIdx.x >= s) val += sh[cur][threadIdx.x - s];
        sh[cur ^ 1][threadIdx.x] = val;
        cur ^= 1;
        __syncthreads();
    }
    if (threadIdx.x < NB_SCAN) boff[threadIdx.x] = sh[cur][threadIdx.x] - v;
}

__global__ void k_scan2(const int* __restrict__ cnt, const int* __restrict__ boff,
                        int* __restrict__ off) {
    __shared__ int sh[2][256];
    int i = blockIdx.x * 256 + threadIdx.x;
    int v = (i < NN) ? cnt[i] : 0;
    int cur = 0;
    sh[0][threadIdx.x] = v;
    __syncthreads();
    for (int s = 1; s < 256; s <<= 1) {
        int val = sh[cur][threadIdx.x];
        if ((int)threadIdx.x >= s) val += sh[cur][threadIdx.x - s];
        sh[cur ^ 1][threadIdx.x] = val;
        cur ^= 1;
        __syncthreads();
    }
    if (i < NN) off[i] = boff[blockIdx.x] + sh[cur][threadIdx.x] - v;
}

__global__ void k_fill(const int* __restrict__ row, const int* __restrict__ col,
                       const float* __restrict__ dh, const int* __restrict__ off,
                       int* __restrict__ cursor, ll* __restrict__ csrp) {
    int e = blockIdx.x * blockDim.x + threadIdx.x;
    if (e >= NE) return;
    int r = row[e], c = col[e];
    int pos = off[c] + atomicAdd(&cursor[c], 1);
    float w = dh[r] * dh[c];
    csrp[pos] = ((ll)__float_as_int(w) << 32) | (unsigned int)r;
}

// fp32 -> fp16 plane copy (phase-2 gather table init)
__global__ void k_tohalf(const float* __restrict__ src, _Float16* __restrict__ dst) {
    size_t i = ((size_t)blockIdx.x * 256 + threadIdx.x) * 4;
    float4 v = *(const float4*)&src[i];
    *(h4_t*)&dst[i] = f4h4(v);
}

// ---------------- phase-1 recurrence (R0-validated, fp32 [NN][64]) ----------

template <bool INIT>
__global__ __launch_bounds__(256) void k_prop(
    const float* __restrict__ Tcur, const float* __restrict__ Tprev,
    float* __restrict__ Tnext, const int* __restrict__ off,
    const int* __restrict__ degi, const ll* __restrict__ csrp) {
    int node = blockIdx.x * 4 + (threadIdx.x >> 6);
    int lane = threadIdx.x & 63;
    int eg = lane >> 4;
    int cq = lane & 15;
    int s = off[node], e = s + degi[node];
    const float* tb = Tcur + (size_t)cq * 4;
    float4 a0 = make_float4(0.f, 0.f, 0.f, 0.f);
    float4 a1 = make_float4(0.f, 0.f, 0.f, 0.f);
    float4 pv = INIT ? make_float4(0.f, 0.f, 0.f, 0.f)
                     : *(const float4*)&Tprev[(size_t)node * 64 + cq * 4];
    int i = s;
    for (; i + 8 <= e; i += 8) {
        int r0, r1; float w0, w1;
        unpack(csrp[i + eg], r0, w0);
        unpack(csrp[i + 4 + eg], r1, w1);
        float4 v0 = *(const float4*)(tb + (size_t)r0 * 64);
        float4 v1 = *(const float4*)(tb + (size_t)r1 * 64);
        a0 = f4fma(w0, v0, a0);
        a1 = f4fma(w1, v1, a1);
    }
    for (; i < e; i += 4) {
        int idx = i + eg;
        bool act = idx < e;
        int r; float w;
        unpack(csrp[act ? idx : (e - 1)], r, w);
        if (!act) w = 0.f;
        float4 v = *(const float4*)(tb + (size_t)r * 64);
        a0 = f4fma(w, v, a0);
    }
    float4 g = make_float4(a0.x + a1.x, a0.y + a1.y, a0.z + a1.z, a0.w + a1.w);
    g.x += __shfl_xor(g.x, 16); g.y += __shfl_xor(g.y, 16);
    g.z += __shfl_xor(g.z, 16); g.w += __shfl_xor(g.w, 16);
    g.x += __shfl_xor(g.x, 32); g.y += __shfl_xor(g.y, 32);
    g.z += __shfl_xor(g.z, 32); g.w += __shfl_xor(g.w, 32);
    float4 t;
    if (INIT) {
        t = make_float4(-g.x, -g.y, -g.z, -g.w);
    } else {
        t = make_float4(-2.f * g.x - pv.x, -2.f * g.y - pv.y,
                        -2.f * g.z - pv.z, -2.f * g.w - pv.w);
    }
    if (eg == 0) *(float4*)&Tnext[(size_t)node * 64 + cq * 4] = t;
}

// ---------------- phase-2 recurrence, single fp16 chain (fallback) ----------
// h8 geometry: lane = eg*8 + cq; 8 edge slots, 8 lanes/edge, 16 B/lane.

template <bool INIT>
__global__ __launch_bounds__(256) void k_prop16(
    const _Float16* __restrict__ Tcur, const _Float16* __restrict__ Tprev,
    _Float16* __restrict__ Tnext, const int* __restrict__ off,
    const int* __restrict__ degi, const ll* __restrict__ csrp) {
    int node = blockIdx.x * 4 + (threadIdx.x >> 6);
    int lane = threadIdx.x & 63;
    int eg = lane >> 3;
    int cq = lane & 7;
    int s = off[node], e = s + degi[node];
    const _Float16* tb = Tcur + (size_t)cq * 8;
    float accA[8], accB[8];
#pragma unroll
    for (int j = 0; j < 8; ++j) { accA[j] = 0.f; accB[j] = 0.f; }
    int i = s;
    for (; i + 16 <= e; i += 16) {
        int r0, r1; float w0, w1;
        unpack(csrp[i + eg], r0, w0);
        unpack(csrp[i + 8 + eg], r1, w1);
        h8_t h0 = *(const h8_t*)(tb + (size_t)r0 * 64);
        h8_t h1 = *(const h8_t*)(tb + (size_t)r1 * 64);
#pragma unroll
        for (int j = 0; j < 8; ++j) accA[j] += w0 * (float)h0[j];
#pragma unroll
        for (int j = 0; j < 8; ++j) accB[j] += w1 * (float)h1[j];
    }
    for (; i < e; i += 8) {
        int idx = i + eg;
        bool act = idx < e;
        int r; float w;
        unpack(csrp[act ? idx : (e - 1)], r, w);
        if (!act) w = 0.f;
        h8_t h = *(const h8_t*)(tb + (size_t)r * 64);
#pragma unroll
        for (int j = 0; j < 8; ++j) accA[j] += w * (float)h[j];
    }
    float g[8];
#pragma unroll
    for (int j = 0; j < 8; ++j) g[j] = accA[j] + accB[j];
#pragma unroll
    for (int j = 0; j < 8; ++j) {
        g[j] += __shfl_xor(g[j], 8);
        g[j] += __shfl_xor(g[j], 16);
        g[j] += __shfl_xor(g[j], 32);
    }
    if (eg == 0) {
        size_t o = (size_t)node * 64 + (size_t)cq * 8;
        h8_t t;
        if (INIT) {
#pragma unroll
            for (int j = 0; j < 8; ++j) t[j] = (_Float16)(-g[j]);
        } else {
            h8_t ph = *(const h8_t*)&Tprev[o];
#pragma unroll
            for (int j = 0; j < 8; ++j)
                t[j] = (_Float16)(-2.f * g[j] - (float)ph[j]);
        }
        *(h8_t*)&Tnext[o] = t;
    }
}

// ---------------- phase-2 merged: 3 fp16 chains, one csrp stream ------------
// Per edge, one unpack feeds h8 gathers from 3 planes (stride CHAIN_ELEMS).
// 3x requested bytes per wave pushes the under-utilized fp16 prop (4.2 TB/s)
// back onto the ~6.5 TB/s gather wall; index/loop/reduce overhead amortized 3x.
// Per-plane edge partition, unroll, reduce tree identical to k_prop16 -> the
// per-plane outputs are bit-identical to the unmerged chains.

template <bool INIT>
__global__ __launch_bounds__(256) void k_prop16x3(
    const _Float16* __restrict__ Tcur, const _Float16* __restrict__ Tprev,
    _Float16* __restrict__ Tnext, const int* __restrict__ off,
    const int* __restrict__ degi, const ll* __restrict__ csrp) {
    int node = blockIdx.x * 4 + (threadIdx.x >> 6);
    int lane = threadIdx.x & 63;
    int eg = lane >> 3;
    int cq = lane & 7;
    int s = off[node], e = s + degi[node];
    const _Float16* tb0 = Tcur + (size_t)cq * 8;
    const _Float16* tb1 = tb0 + CHAIN_ELEMS;
    const _Float16* tb2 = tb0 + 2 * CHAIN_ELEMS;
    float aA[3][8], aB[3][8];
#pragma unroll
    for (int p = 0; p < 3; ++p)
#pragma unroll
        for (int j = 0; j < 8; ++j) { aA[p][j] = 0.f; aB[p][j] = 0.f; }
    int i = s;
    for (; i + 16 <= e; i += 16) {
        int r0, r1; float w0, w1;
        unpack(csrp[i + eg], r0, w0);
        unpack(csrp[i + 8 + eg], r1, w1);
        size_t o0 = (size_t)r0 * 64, o1 = (size_t)r1 * 64;
        h8_t h00 = *(const h8_t*)(tb0 + o0);
        h8_t h01 = *(const h8_t*)(tb1 + o0);
        h8_t h02 = *(const h8_t*)(tb2 + o0);
        h8_t h10 = *(const h8_t*)(tb0 + o1);
        h8_t h11 = *(const h8_t*)(tb1 + o1);
        h8_t h12 = *(const h8_t*)(tb2 + o1);
#pragma unroll
        for (int j = 0; j < 8; ++j) aA[0][j] += w0 * (float)h00[j];
#pragma unroll
        for (int j = 0; j < 8; ++j) aA[1][j] += w0 * (float)h01[j];
#pragma unroll
        for (int j = 0; j < 8; ++j) aA[2][j] += w0 * (float)h02[j];
#pragma unroll
        for (int j = 0; j < 8; ++j) aB[0][j] += w1 * (float)h10[j];
#pragma unroll
        for (int j = 0; j < 8; ++j) aB[1][j] += w1 * (float)h11[j];
#pragma unroll
        for (int j = 0; j < 8; ++j) aB[2][j] += w1 * (float)h12[j];
    }
    for (; i < e; i += 8) {
        int idx = i + eg;
        bool act = idx < e;
        int r; float w;
        unpack(csrp[act ? idx : (e - 1)], r, w);
        if (!act) w = 0.f;
        size_t o = (size_t)r * 64;
        h8_t h0 = *(const h8_t*)(tb0 + o);
        h8_t h1 = *(const h8_t*)(tb1 + o);
        h8_t h2 = *(const h8_t*)(tb2 + o);
#pragma unroll
        for (int j = 0; j < 8; ++j) aA[0][j] += w * (float)h0[j];
#pragma unroll
        for (int j = 0; j < 8; ++j) aA[1][j] += w * (float)h1[j];
#pragma unroll
        for (int j = 0; j < 8; ++j) aA[2][j] += w * (float)h2[j];
    }
    float g[3][8];
#pragma unroll
    for (int p = 0; p < 3; ++p)
#pragma unroll
        for (int j = 0; j < 8; ++j) g[p][j] = aA[p][j] + aB[p][j];
#pragma unroll
    for (int p = 0; p < 3; ++p)
#pragma unroll
        for (int j = 0; j < 8; ++j) {
            g[p][j] += __shfl_xor(g[p][j], 8);
            g[p][j] += __shfl_xor(g[p][j], 16);
            g[p][j] += __shfl_xor(g[p][j], 32);
        }
    if (eg == 0) {
        size_t ob = (size_t)node * 64 + (size_t)cq * 8;
#pragma unroll
        for (int p = 0; p < 3; ++p) {
            size_t o = ob + (size_t)p * CHAIN_ELEMS;
            h8_t t;
            if (INIT) {
#pragma unroll
                for (int j = 0; j < 8; ++j) t[j] = (_Float16)(-g[p][j]);
            } else {
                h8_t ph = *(const h8_t*)&Tprev[o];
#pragma unroll
                for (int j = 0; j < 8; ++j)
                    t[j] = (_Float16)(-2.f * g[p][j] - (float)ph[j]);
            }
            *(h8_t*)&Tnext[o] = t;
        }
    }
}

// ---------------- combine: fp32 pool slots (phase 1) ------------------------

struct CombCfg {
    float c0[4];
    float ck[4][8];
    int   plane[4];
};

template <int NS, int NT>
__global__ __launch_bounds__(256) void k_combine(
    const float4* __restrict__ src0, const float4* __restrict__ pool,
    float4* __restrict__ accb, CombCfg cfg, int first, int doabs) {
    size_t v = (size_t)blockIdx.x * 256 + threadIdx.x;   // < NN*16
    float4 tv[NS];
#pragma unroll
    for (int m = 0; m < NS; ++m) tv[m] = pool[(size_t)m * CH4 + v];
    float4 s0 = first ? src0[v] : make_float4(0.f, 0.f, 0.f, 0.f);
#pragma unroll
    for (int t = 0; t < NT; ++t) {
        size_t o = (size_t)cfg.plane[t] * CH4 + v;
        float4 a;
        if (first) {
            float c = cfg.c0[t];
            a = make_float4(c * s0.x, c * s0.y, c * s0.z, c * s0.w);
        } else {
            a = accb[o];
        }
#pragma unroll
        for (int m = 0; m < NS; ++m) a = f4fma(cfg.ck[t][m], tv[m], a);
        if (doabs) a = make_float4(fabsf(a.x), fabsf(a.y), fabsf(a.z), fabsf(a.w));
        accb[o] = a;
    }
}

// ---------------- combine: fp16 pool slots, single-plane (fallback) ---------

template <int NS, int NT>
__global__ __launch_bounds__(256) void k_combine16(
    const float4* __restrict__ src0, const h4_t* __restrict__ pool,
    float4* __restrict__ accb, CombCfg cfg, int first, int doabs) {
    size_t v = (size_t)blockIdx.x * 256 + threadIdx.x;   // < NN*16
    float4 tv[NS];
#pragma unroll
    for (int m = 0; m < NS; ++m) tv[m] = h4f4(pool[(size_t)m * CH4 + v]);
    float4 s0 = first ? src0[v] : make_float4(0.f, 0.f, 0.f, 0.f);
#pragma unroll
    for (int t = 0; t < NT; ++t) {
        size_t o = (size_t)cfg.plane[t] * CH4 + v;
        float4 a;
        if (first) {
            float c = cfg.c0[t];
            a = make_float4(c * s0.x, c * s0.y, c * s0.z, c * s0.w);
        } else {
            a = accb[o];
        }
#pragma unroll
        for (int m = 0; m < NS; ++m) a = f4fma(cfg.ck[t][m], tv[m], a);
        if (doabs) a = make_float4(fabsf(a.x), fabsf(a.y), fabsf(a.z), fabsf(a.w));
        accb[o] = a;
    }
}

// ---------------- merged combine: 6 targets, 3-plane fp16 slots -------------
// Slot m (ring of 4) holds T_{k-3+m}; coefficients ck[t][m] follow the same
// ascending-k order as the fallback path -> bit-identical accumulation.
//   t: (srcplane, acc2 plane) = (0,0) (0,1) (0,3) (1,2) (1,4) (2,5)

struct Comb316Cfg {
    float c0[6];
    float ck[6][4];
};

__global__ __launch_bounds__(256) void k_comb316(
    const float4* __restrict__ src0, const h4_t* __restrict__ pool,
    float4* __restrict__ accb, Comb316Cfg cfg, int first, int doabs) {
    size_t v = (size_t)blockIdx.x * 256 + threadIdx.x;   // < NN*16
    float4 tv[4][3];
#pragma unroll
    for (int m = 0; m < 4; ++m)
#pragma unroll
        for (int sp = 0; sp < 3; ++sp)
            tv[m][sp] = h4f4(pool[((size_t)m * 3 + sp) * CH4 + v]);
    float4 s0[3];
    if (first) {
#pragma unroll
        for (int sp = 0; sp < 3; ++sp) s0[sp] = src0[(size_t)sp * CH4 + v];
    }
    const int SP[6] = {0, 0, 0, 1, 1, 2};
    const int PL[6] = {0, 1, 3, 2, 4, 5};
#pragma unroll
    for (int t = 0; t < 6; ++t) {
        size_t o = (size_t)PL[t] * CH4 + v;
        float4 a;
        if (first) {
            float c = cfg.c0[t];
            float4 s = s0[SP[t]];
            a = make_float4(c * s.x, c * s.y, c * s.z, c * s.w);
        } else {
            a = accb[o];
        }
#pragma unroll
        for (int m = 0; m < 4; ++m) a = f4fma(cfg.ck[t][m], tv[m][SP[t]], a);
        if (doabs) a = make_float4(fabsf(a.x), fabsf(a.y), fabsf(a.z), fabsf(a.w));
        accb[o] = a;
    }
}

// ---------------- moments: two-pass (chunked partials + finalize) -----------

__global__ void k_mompart(const float* __restrict__ x, const float* __restrict__ hacc,
                          const float* __restrict__ acc2, double* __restrict__ pmom) {
    int g = blockIdx.y;
    int c = blockIdx.z;
    int col = blockIdx.x * 256 + threadIdx.x;
    if (col >= 704) return;
    const float* src;
    int c0;
    if (col < 64)       { src = x;    c0 = col; }
    else if (col < 320) { int p = (col - 64) >> 6;  src = hacc + (size_t)p * CHAIN_ELEMS; c0 = (col - 64) & 63; }
    else                { int p = (col - 320) >> 6; src = acc2 + (size_t)p * CHAIN_ELEMS; c0 = (col - 320) & 63; }
    double s1 = 0, s2 = 0, s3 = 0, s4 = 0;
    int base = g * NPG + c * NPC;
    for (int i = 0; i < NPC; ++i) {
        double v = (double)src[(size_t)(base + i) * 64 + c0];
        double v2 = v * v;
        s1 += v; s2 += v2; s3 += v2 * v; s4 += v2 * v2;
    }
    size_t ob = (((size_t)c * NGRAPH + g) * 704 + col) * 4;
    pmom[ob + 0] = s1;
    pmom[ob + 1] = s2;
    pmom[ob + 2] = s3;
    pmom[ob + 3] = s4;
}

__global__ void k_momfin(const double* __restrict__ pmom, float* __restrict__ out) {
    int g = blockIdx.y;
    int col = blockIdx.x * 256 + threadIdx.x;
    if (col >= 704) return;
    double s1 = 0, s2 = 0, s3 = 0, s4 = 0;
    for (int c = 0; c < NCHUNK; ++c) {
        size_t ob = (((size_t)c * NGRAPH + g) * 704 + col) * 4;
        s1 += pmom[ob + 0];
        s2 += pmom[ob + 1];
        s3 += pmom[ob + 2];
        s4 += pmom[ob + 3];
    }
    double n = (double)NPG;
    double mu = s1 / n;
    double E2 = s2 / n, E3 = s3 / n, E4 = s4 / n;
    double m2 = E2 - mu * mu;
    double m3 = E3 - 3.0 * mu * E2 + 2.0 * mu * mu * mu;
    double m4 = E4 - 4.0 * mu * E3 + 6.0 * mu * mu * E2 - 3.0 * mu * mu * mu * mu;
    float m2f = (float)m2;
    float skew = 0.f, kurt = -3.f;
    if (m2f > 0.f) {
        skew = (float)(m3 / (m2 * sqrt(m2)));
        if (skew > 1e15f) skew = 0.f;
        kurt = (float)(m4 / (m2 * m2) - 3.0);
        if (kurt > 1e15f) kurt = -3.f;
    }
    size_t ob = (size_t)g * 2816 + col;
    out[ob]        = (float)mu;
    out[ob + 704]  = m2f;
    out[ob + 1408] = skew;
    out[ob + 2112] = kurt;
}

// ---------------- host ----------------

extern "C" void kernel_launch(void* const* d_in, const int* in_sizes, int n_in,
                              void* d_out, int out_size, void* d_ws, size_t ws_size,
                              hipStream_t stream) {
    const float* x = (const float*)d_in[0];
    const int* ei  = (const int*)d_in[1];
    const int* row = ei;
    const int* col = ei + NE;
    float* out = (float*)d_out;

    // Chebyshev coefficients [17][4], double precision (matches numpy)
    float C[17][4];
    {
        const int Nc = 17;
        const int scales[4] = {2, 4, 8, 16};
        for (int si = 0; si < 4; ++si) {
            double ker[17];
            for (int j = 0; j < Nc; ++j) {
                double num = cos(M_PI * (j + 0.5) / Nc);
                double b = -num;
                double v = pow(b, (double)(scales[si] / 2)) - pow(b, (double)scales[si]);
                if (v < 0) v = 0;
                ker[j] = sqrt(v);
            }
            for (int o = 0; o < Nc; ++o) {
                double acc = 0;
                for (int j = 0; j < Nc; ++j) acc += ker[j] * cos(M_PI * o * (j + 0.5) / Nc);
                C[o][si] = (float)(2.0 / Nc * acc);
            }
        }
    }

    // workspace carve. CAD1 = CAD2 = 4 (min for the T_{k-2} ring). pmom
    // aliases the phase-1 pool (dead by moments time).
    //   plan A: merged phase-2, pool16 = 4 x 3 planes  (~283 MB)
    //   plan B: unmerged,       pool16 = 4 x 1 plane   (~231 MB)
    int*   degi; float* dh; int* off; int* cursor; int* bsum; int* boff;
    ll*    csrp; float* pool; _Float16* pool16; _Float16* h16;
    float* hacc; float* acc2; double* pmom;
    int MERGED = 1;
    for (int attempt = 0; attempt < 2; ++attempt) {
        MERGED = (attempt == 0) ? 1 : 0;
        size_t p16planes = MERGED ? 12 : 4;   // slots x planes
        char* p = (char*)d_ws;
        auto alloc = [&](size_t bytes) -> void* {
            void* r = (void*)p;
            p += (bytes + 255) & ~(size_t)255;
            return r;
        };
        degi   = (int*)alloc((size_t)NN * 4);
        dh     = (float*)alloc((size_t)NN * 4);
        off    = (int*)alloc((size_t)NN * 4);
        cursor = (int*)alloc((size_t)NN * 4);
        bsum   = (int*)alloc((size_t)NB_SCAN * 4);
        boff   = (int*)alloc((size_t)NB_SCAN * 4);
        csrp   = (ll*)alloc((size_t)NE * 8);
        pool   = (float*)alloc((size_t)4 * CHAIN_ELEMS * 4);
        pool16 = (_Float16*)alloc(p16planes * CHAIN_ELEMS * 2);
        h16    = (_Float16*)alloc((size_t)3 * CHAIN_ELEMS * 2);
        hacc   = (float*)alloc((size_t)4 * CHAIN_ELEMS * 4);
        acc2   = (float*)alloc((size_t)6 * CHAIN_ELEMS * 4);
        if ((size_t)(p - (char*)d_ws) <= ws_size) break;
    }
    pmom = (double*)pool;   // alias: pool dead after phase 1

    hipMemsetAsync(degi, 0, (size_t)NN * 4, stream);
    hipMemsetAsync(cursor, 0, (size_t)NN * 4, stream);

    k_deg  <<<(NE + 255) / 256, 256, 0, stream>>>(col, degi);
    k_dh   <<<(NN + 255) / 256, 256, 0, stream>>>(degi, dh);
    k_bsum <<<NB_SCAN, 256, 0, stream>>>(degi, bsum);
    k_bscan<<<1, 256, 0, stream>>>(bsum, boff);
    k_scan2<<<NB_SCAN, 256, 0, stream>>>(degi, boff, off);
    k_fill <<<(NE + 255) / 256, 256, 0, stream>>>(row, col, dh, off, cursor, csrp);

    const int GRID_C = (int)(CH4 / 256);   // 3125

    auto slot = [&](int k) { return pool + (size_t)((k - 1) & 3) * CHAIN_ELEMS; };

    // ---- phase 1: x -> hacc planes 0..3 (|h| per scale), fp32 chain ----
    {
        const int scl[4] = {0, 1, 2, 3};
        const int pln[4] = {0, 1, 2, 3};
        k_prop<true><<<GRID_PROP, 256, 0, stream>>>(x, nullptr, slot(1),
                                                    off, degi, csrp);
        for (int k = 2; k <= 16; ++k) {
            const float* Tprev = (k == 2) ? x : slot(k - 2);
            k_prop<false><<<GRID_PROP, 256, 0, stream>>>(slot(k - 1), Tprev,
                                                         slot(k), off, degi, csrp);
            if ((k % 4) == 0) {
                CombCfg cfg;
                for (int t = 0; t < 4; ++t) {
                    int si = scl[t];
                    cfg.c0[t] = 0.5f * C[0][si];
                    cfg.plane[t] = pln[t];
                    for (int m = 0; m < 4; ++m) cfg.ck[t][m] = C[k - 3 + m][si];
                }
                k_combine<4, 4><<<GRID_C, 256, 0, stream>>>(
                    (const float4*)x, (const float4*)pool, (float4*)hacc,
                    cfg, (k == 4) ? 1 : 0, (k == 16) ? 1 : 0);
            }
        }
    }

    // ---- phase 2: fp16 chains on hacc planes 0..2 -> acc2 ----
    k_tohalf<<<(int)(3 * CHAIN_ELEMS / 1024), 256, 0, stream>>>(hacc, h16);

    if (MERGED) {
        auto slot3 = [&](int k) {
            return pool16 + (size_t)((k - 1) & 3) * 3 * CHAIN_ELEMS;
        };
        k_prop16x3<true><<<GRID_PROP, 256, 0, stream>>>(h16, nullptr, slot3(1),
                                                        off, degi, csrp);
        for (int k = 2; k <= 16; ++k) {
            const _Float16* Tprev = (k == 2) ? h16 : slot3(k - 2);
            k_prop16x3<false><<<GRID_PROP, 256, 0, stream>>>(slot3(k - 1), Tprev,
                                                             slot3(k), off, degi, csrp);
            if ((k % 4) == 0) {
                Comb316Cfg cfg;
                const int SI[6] = {1, 2, 3, 2, 3, 3};
                for (int t = 0; t < 6; ++t) {
                    cfg.c0[t] = 0.5f * C[0][SI[t]];
                    for (int m = 0; m < 4; ++m) cfg.ck[t][m] = C[k - 3 + m][SI[t]];
                }
                k_comb316<<<GRID_C, 256, 0, stream>>>(
                    (const float4*)hacc, (const h4_t*)pool16, (float4*)acc2,
                    cfg, (k == 4) ? 1 : 0, (k == 16) ? 1 : 0);
            }
        }
    } else {
        auto slot16 = [&](int k) {
            return pool16 + (size_t)((k - 1) & 3) * CHAIN_ELEMS;
        };
        auto run_chain16 = [&](int j, const int* scl, const int* pln, int nt) {
            const _Float16* srch = h16 + (size_t)j * CHAIN_ELEMS;
            const float* src0 = hacc + (size_t)j * CHAIN_ELEMS;
            k_prop16<true><<<GRID_PROP, 256, 0, stream>>>(srch, nullptr, slot16(1),
                                                          off, degi, csrp);
            for (int k = 2; k <= 16; ++k) {
                const _Float16* Tprev = (k == 2) ? srch : slot16(k - 2);
                k_prop16<false><<<GRID_PROP, 256, 0, stream>>>(slot16(k - 1), Tprev,
                                                               slot16(k), off, degi, csrp);
                if ((k % 4) == 0) {
                    CombCfg cfg;
                    for (int t = 0; t < nt; ++t) {
                        int si = scl[t];
                        cfg.c0[t] = 0.5f * C[0][si];
                        cfg.plane[t] = pln[t];
                        for (int m = 0; m < 4; ++m) cfg.ck[t][m] = C[k - 3 + m][si];
                    }
                    int first = (k == 4) ? 1 : 0, doabs = (k == 16) ? 1 : 0;
                    if (nt == 3) k_combine16<4, 3><<<GRID_C, 256, 0, stream>>>(
                        (const float4*)src0, (const h4_t*)pool16, (float4*)acc2, cfg, first, doabs);
                    if (nt == 2) k_combine16<4, 2><<<GRID_C, 256, 0, stream>>>(
                        (const float4*)src0, (const h4_t*)pool16, (float4*)acc2, cfg, first, doabs);
                    if (nt == 1) k_combine16<4, 1><<<GRID_C, 256, 0, stream>>>(
                        (const float4*)src0, (const h4_t*)pool16, (float4*)acc2, cfg, first, doabs);
                }
            }
        };
        const int scl0[3] = {1, 2, 3}; const int pln0[3] = {0, 1, 3};
        run_chain16(0, scl0, pln0, 3);
        const int scl1[2] = {2, 3};    const int pln1[2] = {2, 4};
        run_chain16(1, scl1, pln1, 2);
        const int scl2[1] = {3};       const int pln2[1] = {5};
        run_chain16(2, scl2, pln2, 1);
    }

    // ---- moments: two-pass ----
    dim3 mg1(3, NGRAPH, NCHUNK);
    k_mompart<<<mg1, 256, 0, stream>>>(x, hacc, acc2, pmom);
    dim3 mg2(3, NGRAPH);
    k_momfin<<<mg2, 256, 0, stream>>>(pmom, out);
}

// Round 8
// 1788.948 us; speedup vs baseline: 1.0982x; 1.0982x over previous
//
#include <hip/hip_runtime.h>
#include <math.h>

#define NN 50000
#define NE 800000
#define NGRAPH 100
#define NPG 500
#define NB_SCAN 196
#define NCHUNK 5
#define NPC 100                        // nodes per moments chunk
#define CHAIN_ELEMS ((size_t)NN * 64)
#define CH4 ((size_t)NN * 16)          // float4 (or half4) elements per plane
#define GRID_PROP (NN / 4)             // 4 nodes (waves) per 256-thr block

typedef long long ll;
typedef _Float16 h4_t __attribute__((ext_vector_type(4)));
typedef _Float16 h8_t __attribute__((ext_vector_type(8)));

__device__ __forceinline__ void unpack(ll v, int& r, float& w) {
    r = (int)(v & 0xffffffffLL);
    w = __int_as_float((int)(v >> 32));
}

__device__ __forceinline__ float4 f4fma(float w, float4 v, float4 a) {
    a.x += w * v.x; a.y += w * v.y; a.z += w * v.z; a.w += w * v.w;
    return a;
}

__device__ __forceinline__ float4 h4f4(h4_t h) {
    return make_float4((float)h.x, (float)h.y, (float)h.z, (float)h.w);
}

__device__ __forceinline__ h4_t f4h4(float4 v) {
    h4_t h;
    h.x = (_Float16)v.x; h.y = (_Float16)v.y;
    h.z = (_Float16)v.z; h.w = (_Float16)v.w;
    return h;
}

// ---------------- setup kernels ----------------

__global__ void k_deg(const int* __restrict__ col, int* __restrict__ degi) {
    int e = blockIdx.x * blockDim.x + threadIdx.x;
    if (e < NE) atomicAdd(&degi[col[e]], 1);
}

__global__ void k_dh(const int* __restrict__ degi, float* __restrict__ dh) {
    int i = blockIdx.x * blockDim.x + threadIdx.x;
    if (i < NN) {
        int d = degi[i];
        dh[i] = d > 0 ? (float)(1.0 / sqrt((double)d)) : 0.0f;
    }
}

__global__ void k_bsum(const int* __restrict__ cnt, int* __restrict__ bsum) {
    __shared__ int sh[256];
    int i = blockIdx.x * 256 + threadIdx.x;
    sh[threadIdx.x] = (i < NN) ? cnt[i] : 0;
    __syncthreads();
    for (int s = 128; s > 0; s >>= 1) {
        if (threadIdx.x < s) sh[threadIdx.x] += sh[threadIdx.x + s];
        __syncthreads();
    }
    if (threadIdx.x == 0) bsum[blockIdx.x] = sh[0];
}

__global__ void k_bscan(const int* __restrict__ bsum, int* __restrict__ boff) {
    __shared__ int sh[2][256];
    int v = (threadIdx.x < NB_SCAN) ? bsum[threadIdx.x] : 0;
    int cur = 0;
    sh[0][threadIdx.x] = v;
    __syncthreads();
    for (int s = 1; s < 256; s <<= 1) {
        int val = sh[cur][threadIdx.x];
        if ((int)threadIdx.x >= s) val += sh[cur][threadIdx.x - s];
        sh[cur ^ 1][threadIdx.x] = val;
        cur ^= 1;
        __syncthreads();
    }
    if (threadIdx.x < NB_SCAN) boff[threadIdx.x] = sh[cur][threadIdx.x] - v;
}

__global__ void k_scan2(const int* __restrict__ cnt, const int* __restrict__ boff,
                        int* __restrict__ off) {
    __shared__ int sh[2][256];
    int i = blockIdx.x * 256 + threadIdx.x;
    int v = (i < NN) ? cnt[i] : 0;
    int cur = 0;
    sh[0][threadIdx.x] = v;
    __syncthreads();
    for (int s = 1; s < 256; s <<= 1) {
        int val = sh[cur][threadIdx.x];
        if ((int)threadIdx.x >= s) val += sh[cur][threadIdx.x - s];
        sh[cur ^ 1][threadIdx.x] = val;
        cur ^= 1;
        __syncthreads();
    }
    if (i < NN) off[i] = boff[blockIdx.x] + sh[cur][threadIdx.x] - v;
}

__global__ void k_fill(const int* __restrict__ row, const int* __restrict__ col,
                       const float* __restrict__ dh, const int* __restrict__ off,
                       int* __restrict__ cursor, ll* __restrict__ csrp) {
    int e = blockIdx.x * blockDim.x + threadIdx.x;
    if (e >= NE) return;
    int r = row[e], c = col[e];
    int pos = off[c] + atomicAdd(&cursor[c], 1);
    float w = dh[r] * dh[c];
    csrp[pos] = ((ll)__float_as_int(w) << 32) | (unsigned int)r;
}

// fp32 -> fp16 plane copy (phase-2 gather table init)
__global__ void k_tohalf(const float* __restrict__ src, _Float16* __restrict__ dst) {
    size_t i = ((size_t)blockIdx.x * 256 + threadIdx.x) * 4;
    float4 v = *(const float4*)&src[i];
    *(h4_t*)&dst[i] = f4h4(v);
}

// ---------------- phase-1 recurrence (R0-validated, fp32 [NN][64]) ----------

template <bool INIT>
__global__ __launch_bounds__(256) void k_prop(
    const float* __restrict__ Tcur, const float* __restrict__ Tprev,
    float* __restrict__ Tnext, const int* __restrict__ off,
    const int* __restrict__ degi, const ll* __restrict__ csrp) {
    int node = blockIdx.x * 4 + (threadIdx.x >> 6);
    int lane = threadIdx.x & 63;
    int eg = lane >> 4;
    int cq = lane & 15;
    int s = off[node], e = s + degi[node];
    const float* tb = Tcur + (size_t)cq * 4;
    float4 a0 = make_float4(0.f, 0.f, 0.f, 0.f);
    float4 a1 = make_float4(0.f, 0.f, 0.f, 0.f);
    float4 pv = INIT ? make_float4(0.f, 0.f, 0.f, 0.f)
                     : *(const float4*)&Tprev[(size_t)node * 64 + cq * 4];
    int i = s;
    for (; i + 8 <= e; i += 8) {
        int r0, r1; float w0, w1;
        unpack(csrp[i + eg], r0, w0);
        unpack(csrp[i + 4 + eg], r1, w1);
        float4 v0 = *(const float4*)(tb + (size_t)r0 * 64);
        float4 v1 = *(const float4*)(tb + (size_t)r1 * 64);
        a0 = f4fma(w0, v0, a0);
        a1 = f4fma(w1, v1, a1);
    }
    for (; i < e; i += 4) {
        int idx = i + eg;
        bool act = idx < e;
        int r; float w;
        unpack(csrp[act ? idx : (e - 1)], r, w);
        if (!act) w = 0.f;
        float4 v = *(const float4*)(tb + (size_t)r * 64);
        a0 = f4fma(w, v, a0);
    }
    float4 g = make_float4(a0.x + a1.x, a0.y + a1.y, a0.z + a1.z, a0.w + a1.w);
    g.x += __shfl_xor(g.x, 16); g.y += __shfl_xor(g.y, 16);
    g.z += __shfl_xor(g.z, 16); g.w += __shfl_xor(g.w, 16);
    g.x += __shfl_xor(g.x, 32); g.y += __shfl_xor(g.y, 32);
    g.z += __shfl_xor(g.z, 32); g.w += __shfl_xor(g.w, 32);
    float4 t;
    if (INIT) {
        t = make_float4(-g.x, -g.y, -g.z, -g.w);
    } else {
        t = make_float4(-2.f * g.x - pv.x, -2.f * g.y - pv.y,
                        -2.f * g.z - pv.z, -2.f * g.w - pv.w);
    }
    if (eg == 0) *(float4*)&Tnext[(size_t)node * 64 + cq * 4] = t;
}

// ---------------- phase-2 recurrence, single fp16 chain (fallback) ----------

template <bool INIT>
__global__ __launch_bounds__(256) void k_prop16(
    const _Float16* __restrict__ Tcur, const _Float16* __restrict__ Tprev,
    _Float16* __restrict__ Tnext, const int* __restrict__ off,
    const int* __restrict__ degi, const ll* __restrict__ csrp) {
    int node = blockIdx.x * 4 + (threadIdx.x >> 6);
    int lane = threadIdx.x & 63;
    int eg = lane >> 3;
    int cq = lane & 7;
    int s = off[node], e = s + degi[node];
    const _Float16* tb = Tcur + (size_t)cq * 8;
    float accA[8], accB[8];
#pragma unroll
    for (int j = 0; j < 8; ++j) { accA[j] = 0.f; accB[j] = 0.f; }
    int i = s;
    for (; i + 16 <= e; i += 16) {
        int r0, r1; float w0, w1;
        unpack(csrp[i + eg], r0, w0);
        unpack(csrp[i + 8 + eg], r1, w1);
        h8_t h0 = *(const h8_t*)(tb + (size_t)r0 * 64);
        h8_t h1 = *(const h8_t*)(tb + (size_t)r1 * 64);
#pragma unroll
        for (int j = 0; j < 8; ++j) accA[j] += w0 * (float)h0[j];
#pragma unroll
        for (int j = 0; j < 8; ++j) accB[j] += w1 * (float)h1[j];
    }
    for (; i < e; i += 8) {
        int idx = i + eg;
        bool act = idx < e;
        int r; float w;
        unpack(csrp[act ? idx : (e - 1)], r, w);
        if (!act) w = 0.f;
        h8_t h = *(const h8_t*)(tb + (size_t)r * 64);
#pragma unroll
        for (int j = 0; j < 8; ++j) accA[j] += w * (float)h[j];
    }
    float g[8];
#pragma unroll
    for (int j = 0; j < 8; ++j) g[j] = accA[j] + accB[j];
#pragma unroll
    for (int j = 0; j < 8; ++j) {
        g[j] += __shfl_xor(g[j], 8);
        g[j] += __shfl_xor(g[j], 16);
        g[j] += __shfl_xor(g[j], 32);
    }
    if (eg == 0) {
        size_t o = (size_t)node * 64 + (size_t)cq * 8;
        h8_t t;
        if (INIT) {
#pragma unroll
            for (int j = 0; j < 8; ++j) t[j] = (_Float16)(-g[j]);
        } else {
            h8_t ph = *(const h8_t*)&Tprev[o];
#pragma unroll
            for (int j = 0; j < 8; ++j)
                t[j] = (_Float16)(-2.f * g[j] - (float)ph[j]);
        }
        *(h8_t*)&Tnext[o] = t;
    }
}

// ---------------- phase-2 merged: 3 fp16 chains, one csrp stream ------------
// Per edge, one unpack feeds h8 gathers from 3 planes (stride CHAIN_ELEMS).
// Per-plane edge partition, unroll, reduce tree identical to k_prop16 -> the
// per-plane outputs are bit-identical to the unmerged chains.

template <bool INIT>
__global__ __launch_bounds__(256) void k_prop16x3(
    const _Float16* __restrict__ Tcur, const _Float16* __restrict__ Tprev,
    _Float16* __restrict__ Tnext, const int* __restrict__ off,
    const int* __restrict__ degi, const ll* __restrict__ csrp) {
    int node = blockIdx.x * 4 + (threadIdx.x >> 6);
    int lane = threadIdx.x & 63;
    int eg = lane >> 3;
    int cq = lane & 7;
    int s = off[node], e = s + degi[node];
    const _Float16* tb0 = Tcur + (size_t)cq * 8;
    const _Float16* tb1 = tb0 + CHAIN_ELEMS;
    const _Float16* tb2 = tb0 + 2 * CHAIN_ELEMS;
    float aA[3][8], aB[3][8];
#pragma unroll
    for (int p = 0; p < 3; ++p)
#pragma unroll
        for (int j = 0; j < 8; ++j) { aA[p][j] = 0.f; aB[p][j] = 0.f; }
    int i = s;
    for (; i + 16 <= e; i += 16) {
        int r0, r1; float w0, w1;
        unpack(csrp[i + eg], r0, w0);
        unpack(csrp[i + 8 + eg], r1, w1);
        size_t o0 = (size_t)r0 * 64, o1 = (size_t)r1 * 64;
        h8_t h00 = *(const h8_t*)(tb0 + o0);
        h8_t h01 = *(const h8_t*)(tb1 + o0);
        h8_t h02 = *(const h8_t*)(tb2 + o0);
        h8_t h10 = *(const h8_t*)(tb0 + o1);
        h8_t h11 = *(const h8_t*)(tb1 + o1);
        h8_t h12 = *(const h8_t*)(tb2 + o1);
#pragma unroll
        for (int j = 0; j < 8; ++j) aA[0][j] += w0 * (float)h00[j];
#pragma unroll
        for (int j = 0; j < 8; ++j) aA[1][j] += w0 * (float)h01[j];
#pragma unroll
        for (int j = 0; j < 8; ++j) aA[2][j] += w0 * (float)h02[j];
#pragma unroll
        for (int j = 0; j < 8; ++j) aB[0][j] += w1 * (float)h10[j];
#pragma unroll
        for (int j = 0; j < 8; ++j) aB[1][j] += w1 * (float)h11[j];
#pragma unroll
        for (int j = 0; j < 8; ++j) aB[2][j] += w1 * (float)h12[j];
    }
    for (; i < e; i += 8) {
        int idx = i + eg;
        bool act = idx < e;
        int r; float w;
        unpack(csrp[act ? idx : (e - 1)], r, w);
        if (!act) w = 0.f;
        size_t o = (size_t)r * 64;
        h8_t h0 = *(const h8_t*)(tb0 + o);
        h8_t h1 = *(const h8_t*)(tb1 + o);
        h8_t h2 = *(const h8_t*)(tb2 + o);
#pragma unroll
        for (int j = 0; j < 8; ++j) aA[0][j] += w * (float)h0[j];
#pragma unroll
        for (int j = 0; j < 8; ++j) aA[1][j] += w * (float)h1[j];
#pragma unroll
        for (int j = 0; j < 8; ++j) aA[2][j] += w * (float)h2[j];
    }
    float g[3][8];
#pragma unroll
    for (int p = 0; p < 3; ++p)
#pragma unroll
        for (int j = 0; j < 8; ++j) g[p][j] = aA[p][j] + aB[p][j];
#pragma unroll
    for (int p = 0; p < 3; ++p)
#pragma unroll
        for (int j = 0; j < 8; ++j) {
            g[p][j] += __shfl_xor(g[p][j], 8);
            g[p][j] += __shfl_xor(g[p][j], 16);
            g[p][j] += __shfl_xor(g[p][j], 32);
        }
    if (eg == 0) {
        size_t ob = (size_t)node * 64 + (size_t)cq * 8;
#pragma unroll
        for (int p = 0; p < 3; ++p) {
            size_t o = ob + (size_t)p * CHAIN_ELEMS;
            h8_t t;
            if (INIT) {
#pragma unroll
                for (int j = 0; j < 8; ++j) t[j] = (_Float16)(-g[p][j]);
            } else {
                h8_t ph = *(const h8_t*)&Tprev[o];
#pragma unroll
                for (int j = 0; j < 8; ++j)
                    t[j] = (_Float16)(-2.f * g[p][j] - (float)ph[j]);
            }
            *(h8_t*)&Tnext[o] = t;
        }
    }
}

// ---------------- combine: fp32 pool slots (phase 1) ------------------------

struct CombCfg {
    float c0[4];
    float ck[4][8];
    int   plane[4];
};

template <int NS, int NT>
__global__ __launch_bounds__(256) void k_combine(
    const float4* __restrict__ src0, const float4* __restrict__ pool,
    float4* __restrict__ accb, CombCfg cfg, int first, int doabs) {
    size_t v = (size_t)blockIdx.x * 256 + threadIdx.x;   // < NN*16
    float4 tv[NS];
#pragma unroll
    for (int m = 0; m < NS; ++m) tv[m] = pool[(size_t)m * CH4 + v];
    float4 s0 = first ? src0[v] : make_float4(0.f, 0.f, 0.f, 0.f);
#pragma unroll
    for (int t = 0; t < NT; ++t) {
        size_t o = (size_t)cfg.plane[t] * CH4 + v;
        float4 a;
        if (first) {
            float c = cfg.c0[t];
            a = make_float4(c * s0.x, c * s0.y, c * s0.z, c * s0.w);
        } else {
            a = accb[o];
        }
#pragma unroll
        for (int m = 0; m < NS; ++m) a = f4fma(cfg.ck[t][m], tv[m], a);
        if (doabs) a = make_float4(fabsf(a.x), fabsf(a.y), fabsf(a.z), fabsf(a.w));
        accb[o] = a;
    }
}

// ---------------- combine: fp16 pool slots, single-plane (fallback) ---------

template <int NS, int NT>
__global__ __launch_bounds__(256) void k_combine16(
    const float4* __restrict__ src0, const h4_t* __restrict__ pool,
    float4* __restrict__ accb, CombCfg cfg, int first, int doabs) {
    size_t v = (size_t)blockIdx.x * 256 + threadIdx.x;   // < NN*16
    float4 tv[NS];
#pragma unroll
    for (int m = 0; m < NS; ++m) tv[m] = h4f4(pool[(size_t)m * CH4 + v]);
    float4 s0 = first ? src0[v] : make_float4(0.f, 0.f, 0.f, 0.f);
#pragma unroll
    for (int t = 0; t < NT; ++t) {
        size_t o = (size_t)cfg.plane[t] * CH4 + v;
        float4 a;
        if (first) {
            float c = cfg.c0[t];
            a = make_float4(c * s0.x, c * s0.y, c * s0.z, c * s0.w);
        } else {
            a = accb[o];
        }
#pragma unroll
        for (int m = 0; m < NS; ++m) a = f4fma(cfg.ck[t][m], tv[m], a);
        if (doabs) a = make_float4(fabsf(a.x), fabsf(a.y), fabsf(a.z), fabsf(a.w));
        accb[o] = a;
    }
}

// ---------------- merged combine: 6 targets, 3-plane fp16 slots -------------
// Slot m (ring of 4) holds T_{k-3+m}; ck[t][m] ascending-k as fallback path
// -> bit-identical accumulation.
//   t: (srcplane, acc2 plane) = (0,0) (0,1) (0,3) (1,2) (1,4) (2,5)

struct Comb316Cfg {
    float c0[6];
    float ck[6][4];
};

__global__ __launch_bounds__(256) void k_comb316(
    const float4* __restrict__ src0, const h4_t* __restrict__ pool,
    float4* __restrict__ accb, Comb316Cfg cfg, int first, int doabs) {
    size_t v = (size_t)blockIdx.x * 256 + threadIdx.x;   // < NN*16
    float4 tv[4][3];
#pragma unroll
    for (int m = 0; m < 4; ++m)
#pragma unroll
        for (int sp = 0; sp < 3; ++sp)
            tv[m][sp] = h4f4(pool[((size_t)m * 3 + sp) * CH4 + v]);
    float4 s0[3];
    if (first) {
#pragma unroll
        for (int sp = 0; sp < 3; ++sp) s0[sp] = src0[(size_t)sp * CH4 + v];
    }
    const int SP[6] = {0, 0, 0, 1, 1, 2};
    const int PL[6] = {0, 1, 3, 2, 4, 5};
#pragma unroll
    for (int t = 0; t < 6; ++t) {
        size_t o = (size_t)PL[t] * CH4 + v;
        float4 a;
        if (first) {
            float c = cfg.c0[t];
            float4 s = s0[SP[t]];
            a = make_float4(c * s.x, c * s.y, c * s.z, c * s.w);
        } else {
            a = accb[o];
        }
#pragma unroll
        for (int m = 0; m < 4; ++m) a = f4fma(cfg.ck[t][m], tv[m][SP[t]], a);
        if (doabs) a = make_float4(fabsf(a.x), fabsf(a.y), fabsf(a.z), fabsf(a.w));
        accb[o] = a;
    }
}

// ---------------- moments: two-pass (chunked partials + finalize) -----------

__global__ void k_mompart(const float* __restrict__ x, const float* __restrict__ hacc,
                          const float* __restrict__ acc2, double* __restrict__ pmom) {
    int g = blockIdx.y;
    int c = blockIdx.z;
    int col = blockIdx.x * 256 + threadIdx.x;
    if (col >= 704) return;
    const float* src;
    int c0;
    if (col < 64)       { src = x;    c0 = col; }
    else if (col < 320) { int p = (col - 64) >> 6;  src = hacc + (size_t)p * CHAIN_ELEMS; c0 = (col - 64) & 63; }
    else                { int p = (col - 320) >> 6; src = acc2 + (size_t)p * CHAIN_ELEMS; c0 = (col - 320) & 63; }
    double s1 = 0, s2 = 0, s3 = 0, s4 = 0;
    int base = g * NPG + c * NPC;
    for (int i = 0; i < NPC; ++i) {
        double v = (double)src[(size_t)(base + i) * 64 + c0];
        double v2 = v * v;
        s1 += v; s2 += v2; s3 += v2 * v; s4 += v2 * v2;
    }
    size_t ob = (((size_t)c * NGRAPH + g) * 704 + col) * 4;
    pmom[ob + 0] = s1;
    pmom[ob + 1] = s2;
    pmom[ob + 2] = s3;
    pmom[ob + 3] = s4;
}

__global__ void k_momfin(const double* __restrict__ pmom, float* __restrict__ out) {
    int g = blockIdx.y;
    int col = blockIdx.x * 256 + threadIdx.x;
    if (col >= 704) return;
    double s1 = 0, s2 = 0, s3 = 0, s4 = 0;
    for (int c = 0; c < NCHUNK; ++c) {
        size_t ob = (((size_t)c * NGRAPH + g) * 704 + col) * 4;
        s1 += pmom[ob + 0];
        s2 += pmom[ob + 1];
        s3 += pmom[ob + 2];
        s4 += pmom[ob + 3];
    }
    double n = (double)NPG;
    double mu = s1 / n;
    double E2 = s2 / n, E3 = s3 / n, E4 = s4 / n;
    double m2 = E2 - mu * mu;
    double m3 = E3 - 3.0 * mu * E2 + 2.0 * mu * mu * mu;
    double m4 = E4 - 4.0 * mu * E3 + 6.0 * mu * mu * E2 - 3.0 * mu * mu * mu * mu;
    float m2f = (float)m2;
    float skew = 0.f, kurt = -3.f;
    if (m2f > 0.f) {
        skew = (float)(m3 / (m2 * sqrt(m2)));
        if (skew > 1e15f) skew = 0.f;
        kurt = (float)(m4 / (m2 * m2) - 3.0);
        if (kurt > 1e15f) kurt = -3.f;
    }
    size_t ob = (size_t)g * 2816 + col;
    out[ob]        = (float)mu;
    out[ob + 704]  = m2f;
    out[ob + 1408] = skew;
    out[ob + 2112] = kurt;
}

// ---------------- host ----------------

extern "C" void kernel_launch(void* const* d_in, const int* in_sizes, int n_in,
                              void* d_out, int out_size, void* d_ws, size_t ws_size,
                              hipStream_t stream) {
    const float* x = (const float*)d_in[0];
    const int* ei  = (const int*)d_in[1];
    const int* row = ei;
    const int* col = ei + NE;
    float* out = (float*)d_out;

    // Chebyshev coefficients [17][4], double precision (matches numpy)
    float C[17][4];
    {
        const int Nc = 17;
        const int scales[4] = {2, 4, 8, 16};
        for (int si = 0; si < 4; ++si) {
            double ker[17];
            for (int j = 0; j < Nc; ++j) {
                double num = cos(M_PI * (j + 0.5) / Nc);
                double b = -num;
                double v = pow(b, (double)(scales[si] / 2)) - pow(b, (double)scales[si]);
                if (v < 0) v = 0;
                ker[j] = sqrt(v);
            }
            for (int o = 0; o < Nc; ++o) {
                double acc = 0;
                for (int j = 0; j < Nc; ++j) acc += ker[j] * cos(M_PI * o * (j + 0.5) / Nc);
                C[o][si] = (float)(2.0 / Nc * acc);
            }
        }
    }

    // workspace carve with a TIME-ALIASED union region (R7 bug fix: plan A
    // at 282 MB silently exceeded ws and fell back to the unmerged path).
    // Union holds, at disjoint times:
    //   phase 1:  fp32 pool, 4 slots               (51.2e6 B)
    //   phase 2:  h16 (3 planes) + pool16 slots    (19.2e6 + P16B)
    //   moments:  pmom partials                    (11.3e6 B)
    // Plan A (merged, P16B = 12 planes): total ~231e6 B < 242.5e6 proven fit.
    int*   degi; float* dh; int* off; int* cursor; int* bsum; int* boff;
    ll*    csrp; char* ub = nullptr;
    float* hacc; float* acc2;
    int MERGED = 1;
    const size_t H16B  = (3 * CHAIN_ELEMS * 2 + 255) & ~(size_t)255;
    const size_t POOLB = 4 * CHAIN_ELEMS * 4;
    const size_t PMOMB = (size_t)NCHUNK * NGRAPH * 704 * 4 * 8;
    for (int attempt = 0; attempt < 2; ++attempt) {
        MERGED = (attempt == 0) ? 1 : 0;
        size_t P16B = (MERGED ? 12 : 4) * CHAIN_ELEMS * 2;
        size_t UNB = H16B + P16B;
        if (POOLB > UNB) UNB = POOLB;
        if (PMOMB > UNB) UNB = PMOMB;
        char* p = (char*)d_ws;
        auto alloc = [&](size_t bytes) -> void* {
            void* r = (void*)p;
            p += (bytes + 255) & ~(size_t)255;
            return r;
        };
        degi   = (int*)alloc((size_t)NN * 4);
        dh     = (float*)alloc((size_t)NN * 4);
        off    = (int*)alloc((size_t)NN * 4);
        cursor = (int*)alloc((size_t)NN * 4);
        bsum   = (int*)alloc((size_t)NB_SCAN * 4);
        boff   = (int*)alloc((size_t)NB_SCAN * 4);
        csrp   = (ll*)alloc((size_t)NE * 8);
        ub     = (char*)alloc(UNB);
        hacc   = (float*)alloc((size_t)4 * CHAIN_ELEMS * 4);
        acc2   = (float*)alloc((size_t)6 * CHAIN_ELEMS * 4);
        if ((size_t)(p - (char*)d_ws) <= ws_size) break;
    }
    float*    pool   = (float*)ub;                    // phase 1
    _Float16* h16    = (_Float16*)ub;                 // phase 2 (pool dead)
    _Float16* pool16 = (_Float16*)(ub + H16B);        // phase 2
    double*   pmom   = (double*)ub;                   // moments (all dead)

    hipMemsetAsync(degi, 0, (size_t)NN * 4, stream);
    hipMemsetAsync(cursor, 0, (size_t)NN * 4, stream);

    k_deg  <<<(NE + 255) / 256, 256, 0, stream>>>(col, degi);
    k_dh   <<<(NN + 255) / 256, 256, 0, stream>>>(degi, dh);
    k_bsum <<<NB_SCAN, 256, 0, stream>>>(degi, bsum);
    k_bscan<<<1, 256, 0, stream>>>(bsum, boff);
    k_scan2<<<NB_SCAN, 256, 0, stream>>>(degi, boff, off);
    k_fill <<<(NE + 255) / 256, 256, 0, stream>>>(row, col, dh, off, cursor, csrp);

    const int GRID_C = (int)(CH4 / 256);   // 3125

    auto slot = [&](int k) { return pool + (size_t)((k - 1) & 3) * CHAIN_ELEMS; };

    // ---- phase 1: x -> hacc planes 0..3 (|h| per scale), fp32 chain ----
    {
        const int scl[4] = {0, 1, 2, 3};
        const int pln[4] = {0, 1, 2, 3};
        k_prop<true><<<GRID_PROP, 256, 0, stream>>>(x, nullptr, slot(1),
                                                    off, degi, csrp);
        for (int k = 2; k <= 16; ++k) {
            const float* Tprev = (k == 2) ? x : slot(k - 2);
            k_prop<false><<<GRID_PROP, 256, 0, stream>>>(slot(k - 1), Tprev,
                                                         slot(k), off, degi, csrp);
            if ((k % 4) == 0) {
                CombCfg cfg;
                for (int t = 0; t < 4; ++t) {
                    int si = scl[t];
                    cfg.c0[t] = 0.5f * C[0][si];
                    cfg.plane[t] = pln[t];
                    for (int m = 0; m < 4; ++m) cfg.ck[t][m] = C[k - 3 + m][si];
                }
                k_combine<4, 4><<<GRID_C, 256, 0, stream>>>(
                    (const float4*)x, (const float4*)pool, (float4*)hacc,
                    cfg, (k == 4) ? 1 : 0, (k == 16) ? 1 : 0);
            }
        }
    }

    // ---- phase 2: fp16 chains on hacc planes 0..2 -> acc2 ----
    k_tohalf<<<(int)(3 * CHAIN_ELEMS / 1024), 256, 0, stream>>>(hacc, h16);

    if (MERGED) {
        auto slot3 = [&](int k) {
            return pool16 + (size_t)((k - 1) & 3) * 3 * CHAIN_ELEMS;
        };
        k_prop16x3<true><<<GRID_PROP, 256, 0, stream>>>(h16, nullptr, slot3(1),
                                                        off, degi, csrp);
        for (int k = 2; k <= 16; ++k) {
            const _Float16* Tprev = (k == 2) ? h16 : slot3(k - 2);
            k_prop16x3<false><<<GRID_PROP, 256, 0, stream>>>(slot3(k - 1), Tprev,
                                                             slot3(k), off, degi, csrp);
            if ((k % 4) == 0) {
                Comb316Cfg cfg;
                const int SI[6] = {1, 2, 3, 2, 3, 3};
                for (int t = 0; t < 6; ++t) {
                    cfg.c0[t] = 0.5f * C[0][SI[t]];
                    for (int m = 0; m < 4; ++m) cfg.ck[t][m] = C[k - 3 + m][SI[t]];
                }
                k_comb316<<<GRID_C, 256, 0, stream>>>(
                    (const float4*)hacc, (const h4_t*)pool16, (float4*)acc2,
                    cfg, (k == 4) ? 1 : 0, (k == 16) ? 1 : 0);
            }
        }
    } else {
        auto slot16 = [&](int k) {
            return pool16 + (size_t)((k - 1) & 3) * CHAIN_ELEMS;
        };
        auto run_chain16 = [&](int j, const int* scl, const int* pln, int nt) {
            const _Float16* srch = h16 + (size_t)j * CHAIN_ELEMS;
            const float* src0 = hacc + (size_t)j * CHAIN_ELEMS;
            k_prop16<true><<<GRID_PROP, 256, 0, stream>>>(srch, nullptr, slot16(1),
                                                          off, degi, csrp);
            for (int k = 2; k <= 16; ++k) {
                const _Float16* Tprev = (k == 2) ? srch : slot16(k - 2);
                k_prop16<false><<<GRID_PROP, 256, 0, stream>>>(slot16(k - 1), Tprev,
                                                               slot16(k), off, degi, csrp);
                if ((k % 4) == 0) {
                    CombCfg cfg;
                    for (int t = 0; t < nt; ++t) {
                        int si = scl[t];
                        cfg.c0[t] = 0.5f * C[0][si];
                        cfg.plane[t] = pln[t];
                        for (int m = 0; m < 4; ++m) cfg.ck[t][m] = C[k - 3 + m][si];
                    }
                    int first = (k == 4) ? 1 : 0, doabs = (k == 16) ? 1 : 0;
                    if (nt == 3) k_combine16<4, 3><<<GRID_C, 256, 0, stream>>>(
                        (const float4*)src0, (const h4_t*)pool16, (float4*)acc2, cfg, first, doabs);
                    if (nt == 2) k_combine16<4, 2><<<GRID_C, 256, 0, stream>>>(
                        (const float4*)src0, (const h4_t*)pool16, (float4*)acc2, cfg, first, doabs);
                    if (nt == 1) k_combine16<4, 1><<<GRID_C, 256, 0, stream>>>(
                        (const float4*)src0, (const h4_t*)pool16, (float4*)acc2, cfg, first, doabs);
                }
            }
        };
        const int scl0[3] = {1, 2, 3}; const int pln0[3] = {0, 1, 3};
        run_chain16(0, scl0, pln0, 3);
        const int scl1[2] = {2, 3};    const int pln1[2] = {2, 4};
        run_chain16(1, scl1, pln1, 2);
        const int scl2[1] = {3};       const int pln2[1] = {5};
        run_chain16(2, scl2, pln2, 1);
    }

    // ---- moments: two-pass ----
    dim3 mg1(3, NGRAPH, NCHUNK);
    k_mompart<<<mg1, 256, 0, stream>>>(x, hacc, acc2, pmom);
    dim3 mg2(3, NGRAPH);
    k_momfin<<<mg2, 256, 0, stream>>>(pmom, out);
}

// Round 9
// 1705.305 us; speedup vs baseline: 1.1520x; 1.0490x over previous
//
#include <hip/hip_runtime.h>
#include <math.h>

#define NN 50000
#define NE 800000
#define NGRAPH 100
#define NPG 500
#define NB_SCAN 196
#define NCHUNK 5
#define NPC 100                        // nodes per moments chunk
#define CHAIN_ELEMS ((size_t)NN * 64)
#define CH4 ((size_t)NN * 16)          // float4 (or half4) elements per plane
#define GRID_PROP (NN / 4)             // 4 nodes (waves) per 256-thr block

typedef long long ll;
typedef _Float16 h4_t __attribute__((ext_vector_type(4)));
typedef _Float16 h8_t __attribute__((ext_vector_type(8)));

__device__ __forceinline__ void unpack(ll v, int& r, float& w) {
    r = (int)(v & 0xffffffffLL);
    w = __int_as_float((int)(v >> 32));
}

__device__ __forceinline__ float4 f4fma(float w, float4 v, float4 a) {
    a.x += w * v.x; a.y += w * v.y; a.z += w * v.z; a.w += w * v.w;
    return a;
}

__device__ __forceinline__ float4 h4f4(h4_t h) {
    return make_float4((float)h.x, (float)h.y, (float)h.z, (float)h.w);
}

__device__ __forceinline__ h4_t f4h4(float4 v) {
    h4_t h;
    h.x = (_Float16)v.x; h.y = (_Float16)v.y;
    h.z = (_Float16)v.z; h.w = (_Float16)v.w;
    return h;
}

// ---------------- setup kernels ----------------

__global__ void k_deg(const int* __restrict__ col, int* __restrict__ degi) {
    int e = blockIdx.x * blockDim.x + threadIdx.x;
    if (e < NE) atomicAdd(&degi[col[e]], 1);
}

__global__ void k_dh(const int* __restrict__ degi, float* __restrict__ dh) {
    int i = blockIdx.x * blockDim.x + threadIdx.x;
    if (i < NN) {
        int d = degi[i];
        dh[i] = d > 0 ? (float)(1.0 / sqrt((double)d)) : 0.0f;
    }
}

__global__ void k_bsum(const int* __restrict__ cnt, int* __restrict__ bsum) {
    __shared__ int sh[256];
    int i = blockIdx.x * 256 + threadIdx.x;
    sh[threadIdx.x] = (i < NN) ? cnt[i] : 0;
    __syncthreads();
    for (int s = 128; s > 0; s >>= 1) {
        if (threadIdx.x < s) sh[threadIdx.x] += sh[threadIdx.x + s];
        __syncthreads();
    }
    if (threadIdx.x == 0) bsum[blockIdx.x] = sh[0];
}

__global__ void k_bscan(const int* __restrict__ bsum, int* __restrict__ boff) {
    __shared__ int sh[2][256];
    int v = (threadIdx.x < NB_SCAN) ? bsum[threadIdx.x] : 0;
    int cur = 0;
    sh[0][threadIdx.x] = v;
    __syncthreads();
    for (int s = 1; s < 256; s <<= 1) {
        int val = sh[cur][threadIdx.x];
        if ((int)threadIdx.x >= s) val += sh[cur][threadIdx.x - s];
        sh[cur ^ 1][threadIdx.x] = val;
        cur ^= 1;
        __syncthreads();
    }
    if (threadIdx.x < NB_SCAN) boff[threadIdx.x] = sh[cur][threadIdx.x] - v;
}

__global__ void k_scan2(const int* __restrict__ cnt, const int* __restrict__ boff,
                        int* __restrict__ off) {
    __shared__ int sh[2][256];
    int i = blockIdx.x * 256 + threadIdx.x;
    int v = (i < NN) ? cnt[i] : 0;
    int cur = 0;
    sh[0][threadIdx.x] = v;
    __syncthreads();
    for (int s = 1; s < 256; s <<= 1) {
        int val = sh[cur][threadIdx.x];
        if ((int)threadIdx.x >= s) val += sh[cur][threadIdx.x - s];
        sh[cur ^ 1][threadIdx.x] = val;
        cur ^= 1;
        __syncthreads();
    }
    if (i < NN) off[i] = boff[blockIdx.x] + sh[cur][threadIdx.x] - v;
}

__global__ void k_fill(const int* __restrict__ row, const int* __restrict__ col,
                       const float* __restrict__ dh, const int* __restrict__ off,
                       int* __restrict__ cursor, ll* __restrict__ csrp) {
    int e = blockIdx.x * blockDim.x + threadIdx.x;
    if (e >= NE) return;
    int r = row[e], c = col[e];
    int pos = off[c] + atomicAdd(&cursor[c], 1);
    float w = dh[r] * dh[c];
    csrp[pos] = ((ll)__float_as_int(w) << 32) | (unsigned int)r;
}

// ---------------- phase-1 recurrence (R0-validated, fp32 [NN][64]) ----------

template <bool INIT>
__global__ __launch_bounds__(256) void k_prop(
    const float* __restrict__ Tcur, const float* __restrict__ Tprev,
    float* __restrict__ Tnext, const int* __restrict__ off,
    const int* __restrict__ degi, const ll* __restrict__ csrp) {
    int node = blockIdx.x * 4 + (threadIdx.x >> 6);
    int lane = threadIdx.x & 63;
    int eg = lane >> 4;
    int cq = lane & 15;
    int s = off[node], e = s + degi[node];
    const float* tb = Tcur + (size_t)cq * 4;
    float4 a0 = make_float4(0.f, 0.f, 0.f, 0.f);
    float4 a1 = make_float4(0.f, 0.f, 0.f, 0.f);
    float4 pv = INIT ? make_float4(0.f, 0.f, 0.f, 0.f)
                     : *(const float4*)&Tprev[(size_t)node * 64 + cq * 4];
    int i = s;
    for (; i + 8 <= e; i += 8) {
        int r0, r1; float w0, w1;
        unpack(csrp[i + eg], r0, w0);
        unpack(csrp[i + 4 + eg], r1, w1);
        float4 v0 = *(const float4*)(tb + (size_t)r0 * 64);
        float4 v1 = *(const float4*)(tb + (size_t)r1 * 64);
        a0 = f4fma(w0, v0, a0);
        a1 = f4fma(w1, v1, a1);
    }
    for (; i < e; i += 4) {
        int idx = i + eg;
        bool act = idx < e;
        int r; float w;
        unpack(csrp[act ? idx : (e - 1)], r, w);
        if (!act) w = 0.f;
        float4 v = *(const float4*)(tb + (size_t)r * 64);
        a0 = f4fma(w, v, a0);
    }
    float4 g = make_float4(a0.x + a1.x, a0.y + a1.y, a0.z + a1.z, a0.w + a1.w);
    g.x += __shfl_xor(g.x, 16); g.y += __shfl_xor(g.y, 16);
    g.z += __shfl_xor(g.z, 16); g.w += __shfl_xor(g.w, 16);
    g.x += __shfl_xor(g.x, 32); g.y += __shfl_xor(g.y, 32);
    g.z += __shfl_xor(g.z, 32); g.w += __shfl_xor(g.w, 32);
    float4 t;
    if (INIT) {
        t = make_float4(-g.x, -g.y, -g.z, -g.w);
    } else {
        t = make_float4(-2.f * g.x - pv.x, -2.f * g.y - pv.y,
                        -2.f * g.z - pv.z, -2.f * g.w - pv.w);
    }
    if (eg == 0) *(float4*)&Tnext[(size_t)node * 64 + cq * 4] = t;
}

// ---------------- phase-2 merged: 3 fp16 chains, one csrp stream ------------
// (R8-validated: 60 us/dispatch, 3 chains at once.)

template <bool INIT>
__global__ __launch_bounds__(256) void k_prop16x3(
    const _Float16* __restrict__ Tcur, const _Float16* __restrict__ Tprev,
    _Float16* __restrict__ Tnext, const int* __restrict__ off,
    const int* __restrict__ degi, const ll* __restrict__ csrp) {
    int node = blockIdx.x * 4 + (threadIdx.x >> 6);
    int lane = threadIdx.x & 63;
    int eg = lane >> 3;
    int cq = lane & 7;
    int s = off[node], e = s + degi[node];
    const _Float16* tb0 = Tcur + (size_t)cq * 8;
    const _Float16* tb1 = tb0 + CHAIN_ELEMS;
    const _Float16* tb2 = tb0 + 2 * CHAIN_ELEMS;
    float aA[3][8], aB[3][8];
#pragma unroll
    for (int p = 0; p < 3; ++p)
#pragma unroll
        for (int j = 0; j < 8; ++j) { aA[p][j] = 0.f; aB[p][j] = 0.f; }
    int i = s;
    for (; i + 16 <= e; i += 16) {
        int r0, r1; float w0, w1;
        unpack(csrp[i + eg], r0, w0);
        unpack(csrp[i + 8 + eg], r1, w1);
        size_t o0 = (size_t)r0 * 64, o1 = (size_t)r1 * 64;
        h8_t h00 = *(const h8_t*)(tb0 + o0);
        h8_t h01 = *(const h8_t*)(tb1 + o0);
        h8_t h02 = *(const h8_t*)(tb2 + o0);
        h8_t h10 = *(const h8_t*)(tb0 + o1);
        h8_t h11 = *(const h8_t*)(tb1 + o1);
        h8_t h12 = *(const h8_t*)(tb2 + o1);
#pragma unroll
        for (int j = 0; j < 8; ++j) aA[0][j] += w0 * (float)h00[j];
#pragma unroll
        for (int j = 0; j < 8; ++j) aA[1][j] += w0 * (float)h01[j];
#pragma unroll
        for (int j = 0; j < 8; ++j) aA[2][j] += w0 * (float)h02[j];
#pragma unroll
        for (int j = 0; j < 8; ++j) aB[0][j] += w1 * (float)h10[j];
#pragma unroll
        for (int j = 0; j < 8; ++j) aB[1][j] += w1 * (float)h11[j];
#pragma unroll
        for (int j = 0; j < 8; ++j) aB[2][j] += w1 * (float)h12[j];
    }
    for (; i < e; i += 8) {
        int idx = i + eg;
        bool act = idx < e;
        int r; float w;
        unpack(csrp[act ? idx : (e - 1)], r, w);
        if (!act) w = 0.f;
        size_t o = (size_t)r * 64;
        h8_t h0 = *(const h8_t*)(tb0 + o);
        h8_t h1 = *(const h8_t*)(tb1 + o);
        h8_t h2 = *(const h8_t*)(tb2 + o);
#pragma unroll
        for (int j = 0; j < 8; ++j) aA[0][j] += w * (float)h0[j];
#pragma unroll
        for (int j = 0; j < 8; ++j) aA[1][j] += w * (float)h1[j];
#pragma unroll
        for (int j = 0; j < 8; ++j) aA[2][j] += w * (float)h2[j];
    }
    float g[3][8];
#pragma unroll
    for (int p = 0; p < 3; ++p)
#pragma unroll
        for (int j = 0; j < 8; ++j) g[p][j] = aA[p][j] + aB[p][j];
#pragma unroll
    for (int p = 0; p < 3; ++p)
#pragma unroll
        for (int j = 0; j < 8; ++j) {
            g[p][j] += __shfl_xor(g[p][j], 8);
            g[p][j] += __shfl_xor(g[p][j], 16);
            g[p][j] += __shfl_xor(g[p][j], 32);
        }
    if (eg == 0) {
        size_t ob = (size_t)node * 64 + (size_t)cq * 8;
#pragma unroll
        for (int p = 0; p < 3; ++p) {
            size_t o = ob + (size_t)p * CHAIN_ELEMS;
            h8_t t;
            if (INIT) {
#pragma unroll
                for (int j = 0; j < 8; ++j) t[j] = (_Float16)(-g[p][j]);
            } else {
                h8_t ph = *(const h8_t*)&Tprev[o];
#pragma unroll
                for (int j = 0; j < 8; ++j)
                    t[j] = (_Float16)(-2.f * g[p][j] - (float)ph[j]);
            }
            *(h8_t*)&Tnext[o] = t;
        }
    }
}

// ---------------- combine: fp32 pool slots (phase 1) ------------------------
// Optionally emits fp16 copies of planes 0..2 on the final (doabs) pass,
// fusing the old k_tohalf into the combine epilogue.

struct CombCfg {
    float c0[4];
    float ck[4][8];
    int   plane[4];
};

template <int NS, int NT>
__global__ __launch_bounds__(256) void k_combine(
    const float4* __restrict__ src0, const float4* __restrict__ pool,
    float4* __restrict__ accb, _Float16* __restrict__ h16out,
    CombCfg cfg, int first, int doabs) {
    size_t v = (size_t)blockIdx.x * 256 + threadIdx.x;   // < NN*16
    float4 tv[NS];
#pragma unroll
    for (int m = 0; m < NS; ++m) tv[m] = pool[(size_t)m * CH4 + v];
    float4 s0 = first ? src0[v] : make_float4(0.f, 0.f, 0.f, 0.f);
#pragma unroll
    for (int t = 0; t < NT; ++t) {
        size_t o = (size_t)cfg.plane[t] * CH4 + v;
        float4 a;
        if (first) {
            float c = cfg.c0[t];
            a = make_float4(c * s0.x, c * s0.y, c * s0.z, c * s0.w);
        } else {
            a = accb[o];
        }
#pragma unroll
        for (int m = 0; m < NS; ++m) a = f4fma(cfg.ck[t][m], tv[m], a);
        if (doabs) a = make_float4(fabsf(a.x), fabsf(a.y), fabsf(a.z), fabsf(a.w));
        accb[o] = a;
        if (doabs && h16out && cfg.plane[t] < 3) {
            size_t eo = (size_t)cfg.plane[t] * CHAIN_ELEMS + v * 4;
            *(h4_t*)&h16out[eo] = f4h4(a);
        }
    }
}

// ---------------- merged combine: 6 targets, 3-plane fp16 slots -------------
// acc2 is fp16 (3 RMW re-quantizations of partial sums, ~1.5e-3 rel).
//   t: (srcplane, acc2 plane) = (0,0) (0,1) (0,3) (1,2) (1,4) (2,5)

struct Comb316Cfg {
    float c0[6];
    float ck[6][4];
};

__global__ __launch_bounds__(256) void k_comb316(
    const float4* __restrict__ src0, const h4_t* __restrict__ pool,
    h4_t* __restrict__ accb, Comb316Cfg cfg, int first, int doabs) {
    size_t v = (size_t)blockIdx.x * 256 + threadIdx.x;   // < NN*16
    float4 tv[4][3];
#pragma unroll
    for (int m = 0; m < 4; ++m)
#pragma unroll
        for (int sp = 0; sp < 3; ++sp)
            tv[m][sp] = h4f4(pool[((size_t)m * 3 + sp) * CH4 + v]);
    float4 s0[3];
    if (first) {
#pragma unroll
        for (int sp = 0; sp < 3; ++sp) s0[sp] = src0[(size_t)sp * CH4 + v];
    }
    const int SP[6] = {0, 0, 0, 1, 1, 2};
    const int PL[6] = {0, 1, 3, 2, 4, 5};
#pragma unroll
    for (int t = 0; t < 6; ++t) {
        size_t o = (size_t)PL[t] * CH4 + v;
        float4 a;
        if (first) {
            float c = cfg.c0[t];
            float4 s = s0[SP[t]];
            a = make_float4(c * s.x, c * s.y, c * s.z, c * s.w);
        } else {
            a = h4f4(accb[o]);
        }
#pragma unroll
        for (int m = 0; m < 4; ++m) a = f4fma(cfg.ck[t][m], tv[m][SP[t]], a);
        if (doabs) a = make_float4(fabsf(a.x), fabsf(a.y), fabsf(a.z), fabsf(a.w));
        accb[o] = f4h4(a);
    }
}

// ---------------- moments: two-pass (chunked partials + finalize) -----------

__global__ void k_mompart(const float* __restrict__ x, const float* __restrict__ hacc,
                          const _Float16* __restrict__ acc2, double* __restrict__ pmom) {
    int g = blockIdx.y;
    int c = blockIdx.z;
    int col = blockIdx.x * 256 + threadIdx.x;
    if (col >= 704) return;
    int base = g * NPG + c * NPC;
    double s1 = 0, s2 = 0, s3 = 0, s4 = 0;
    if (col < 320) {
        const float* src;
        int c0;
        if (col < 64) { src = x; c0 = col; }
        else { int p = (col - 64) >> 6; src = hacc + (size_t)p * CHAIN_ELEMS; c0 = (col - 64) & 63; }
        for (int i = 0; i < NPC; ++i) {
            double v = (double)src[(size_t)(base + i) * 64 + c0];
            double v2 = v * v;
            s1 += v; s2 += v2; s3 += v2 * v; s4 += v2 * v2;
        }
    } else {
        int p = (col - 320) >> 6;
        int c0 = (col - 320) & 63;
        const _Float16* src = acc2 + (size_t)p * CHAIN_ELEMS;
        for (int i = 0; i < NPC; ++i) {
            double v = (double)(float)src[(size_t)(base + i) * 64 + c0];
            double v2 = v * v;
            s1 += v; s2 += v2; s3 += v2 * v; s4 += v2 * v2;
        }
    }
    size_t ob = (((size_t)c * NGRAPH + g) * 704 + col) * 4;
    pmom[ob + 0] = s1;
    pmom[ob + 1] = s2;
    pmom[ob + 2] = s3;
    pmom[ob + 3] = s4;
}

__global__ void k_momfin(const double* __restrict__ pmom, float* __restrict__ out) {
    int g = blockIdx.y;
    int col = blockIdx.x * 256 + threadIdx.x;
    if (col >= 704) return;
    double s1 = 0, s2 = 0, s3 = 0, s4 = 0;
    for (int c = 0; c < NCHUNK; ++c) {
        size_t ob = (((size_t)c * NGRAPH + g) * 704 + col) * 4;
        s1 += pmom[ob + 0];
        s2 += pmom[ob + 1];
        s3 += pmom[ob + 2];
        s4 += pmom[ob + 3];
    }
    double n = (double)NPG;
    double mu = s1 / n;
    double E2 = s2 / n, E3 = s3 / n, E4 = s4 / n;
    double m2 = E2 - mu * mu;
    double m3 = E3 - 3.0 * mu * E2 + 2.0 * mu * mu * mu;
    double m4 = E4 - 4.0 * mu * E3 + 6.0 * mu * mu * E2 - 3.0 * mu * mu * mu * mu;
    float m2f = (float)m2;
    float skew = 0.f, kurt = -3.f;
    if (m2f > 0.f) {
        skew = (float)(m3 / (m2 * sqrt(m2)));
        if (skew > 1e15f) skew = 0.f;
        kurt = (float)(m4 / (m2 * m2) - 3.0);
        if (kurt > 1e15f) kurt = -3.f;
    }
    size_t ob = (size_t)g * 2816 + col;
    out[ob]        = (float)mu;
    out[ob + 704]  = m2f;
    out[ob + 1408] = skew;
    out[ob + 2112] = kurt;
}

// ---------------- host ----------------

extern "C" void kernel_launch(void* const* d_in, const int* in_sizes, int n_in,
                              void* d_out, int out_size, void* d_ws, size_t ws_size,
                              hipStream_t stream) {
    const float* x = (const float*)d_in[0];
    const int* ei  = (const int*)d_in[1];
    const int* row = ei;
    const int* col = ei + NE;
    float* out = (float*)d_out;

    // Chebyshev coefficients [17][4], double precision (matches numpy)
    float C[17][4];
    {
        const int Nc = 17;
        const int scales[4] = {2, 4, 8, 16};
        for (int si = 0; si < 4; ++si) {
            double ker[17];
            for (int j = 0; j < Nc; ++j) {
                double num = cos(M_PI * (j + 0.5) / Nc);
                double b = -num;
                double v = pow(b, (double)(scales[si] / 2)) - pow(b, (double)scales[si]);
                if (v < 0) v = 0;
                ker[j] = sqrt(v);
            }
            for (int o = 0; o < Nc; ++o) {
                double acc = 0;
                for (int j = 0; j < Nc; ++j) acc += ker[j] * cos(M_PI * o * (j + 0.5) / Nc);
                C[o][si] = (float)(2.0 / Nc * acc);
            }
        }
    }

    // Workspace: union region time-shared between
    //   phase 1:  fp32 pool (CAD1 slots) at [0, POOLB) ; final combine writes
    //             h16 at [H16OFF, H16OFF+H16B) (disjoint from pool)
    //   phase 2:  pool16 (4 slots x 3 planes) at [0, P16B) + h16 (read)
    //   moments:  pmom partials at [0, PMOMB)
    // CAD1=8 plan: union = 102.4+19.2 MB; total ~218 MB (< 242.5 proven fit).
    int*   degi; float* dh; int* off; int* cursor; int* bsum; int* boff;
    ll*    csrp; char* ub = nullptr;
    float* hacc; _Float16* acc2;
    int CAD1 = 8;
    const size_t H16B  = ((size_t)3 * CHAIN_ELEMS * 2 + 255) & ~(size_t)255;
    const size_t P16B  = ((size_t)12 * CHAIN_ELEMS * 2 + 255) & ~(size_t)255;
    const size_t PMOMB = (size_t)NCHUNK * NGRAPH * 704 * 4 * 8;
    size_t H16OFF = 0;
    for (int attempt = 0; attempt < 2; ++attempt) {
        CAD1 = (attempt == 0) ? 8 : 4;
        size_t POOLB = ((size_t)CAD1 * CHAIN_ELEMS * 4 + 255) & ~(size_t)255;
        H16OFF = (POOLB > P16B) ? POOLB : P16B;
        size_t UNB = H16OFF + H16B;
        if (PMOMB > UNB) UNB = PMOMB;
        char* p = (char*)d_ws;
        auto alloc = [&](size_t bytes) -> void* {
            void* r = (void*)p;
            p += (bytes + 255) & ~(size_t)255;
            return r;
        };
        degi   = (int*)alloc((size_t)NN * 4);
        dh     = (float*)alloc((size_t)NN * 4);
        off    = (int*)alloc((size_t)NN * 4);
        cursor = (int*)alloc((size_t)NN * 4);
        bsum   = (int*)alloc((size_t)NB_SCAN * 4);
        boff   = (int*)alloc((size_t)NB_SCAN * 4);
        csrp   = (ll*)alloc((size_t)NE * 8);
        ub     = (char*)alloc(UNB);
        hacc   = (float*)alloc((size_t)4 * CHAIN_ELEMS * 4);
        acc2   = (_Float16*)alloc((size_t)6 * CHAIN_ELEMS * 2);
        if ((size_t)(p - (char*)d_ws) <= ws_size) break;
    }
    float*    pool   = (float*)ub;                 // phase 1 slots
    _Float16* pool16 = (_Float16*)ub;              // phase 2 slots (pool dead)
    _Float16* h16    = (_Float16*)(ub + H16OFF);   // written by final combine
    double*   pmom   = (double*)ub;                // moments (all dead)

    hipMemsetAsync(degi, 0, (size_t)NN * 4, stream);
    hipMemsetAsync(cursor, 0, (size_t)NN * 4, stream);

    k_deg  <<<(NE + 255) / 256, 256, 0, stream>>>(col, degi);
    k_dh   <<<(NN + 255) / 256, 256, 0, stream>>>(degi, dh);
    k_bsum <<<NB_SCAN, 256, 0, stream>>>(degi, bsum);
    k_bscan<<<1, 256, 0, stream>>>(bsum, boff);
    k_scan2<<<NB_SCAN, 256, 0, stream>>>(degi, boff, off);
    k_fill <<<(NE + 255) / 256, 256, 0, stream>>>(row, col, dh, off, cursor, csrp);

    const int GRID_C = (int)(CH4 / 256);   // 3125

    auto slot = [&](int k) {
        return pool + (size_t)((k - 1) & (CAD1 - 1)) * CHAIN_ELEMS;
    };

    // ---- phase 1: x -> hacc planes 0..3 (|h| per scale), fp32 chain ----
    // Memory slot m at combine-step k holds T_{k-CAD1+1+m} (ring identity).
    {
        const int scl[4] = {0, 1, 2, 3};
        k_prop<true><<<GRID_PROP, 256, 0, stream>>>(x, nullptr, slot(1),
                                                    off, degi, csrp);
        for (int k = 2; k <= 16; ++k) {
            const float* Tprev = (k == 2) ? x : slot(k - 2);
            k_prop<false><<<GRID_PROP, 256, 0, stream>>>(slot(k - 1), Tprev,
                                                         slot(k), off, degi, csrp);
            if ((k % CAD1) == 0) {
                CombCfg cfg;
                for (int t = 0; t < 4; ++t) {
                    int si = scl[t];
                    cfg.c0[t] = 0.5f * C[0][si];
                    cfg.plane[t] = t;
                    for (int m = 0; m < CAD1; ++m)
                        cfg.ck[t][m] = C[k - CAD1 + 1 + m][si];
                }
                int first = (k == CAD1) ? 1 : 0;
                int doabs = (k == 16) ? 1 : 0;
                _Float16* ho = doabs ? h16 : nullptr;
                if (CAD1 == 8)
                    k_combine<8, 4><<<GRID_C, 256, 0, stream>>>(
                        (const float4*)x, (const float4*)pool, (float4*)hacc,
                        ho, cfg, first, doabs);
                else
                    k_combine<4, 4><<<GRID_C, 256, 0, stream>>>(
                        (const float4*)x, (const float4*)pool, (float4*)hacc,
                        ho, cfg, first, doabs);
            }
        }
    }

    // ---- phase 2: merged 3-chain fp16 on h16 planes 0..2 -> acc2 (fp16) ----
    {
        auto slot3 = [&](int k) {
            return pool16 + (size_t)((k - 1) & 3) * 3 * CHAIN_ELEMS;
        };
        k_prop16x3<true><<<GRID_PROP, 256, 0, stream>>>(h16, nullptr, slot3(1),
                                                        off, degi, csrp);
        for (int k = 2; k <= 16; ++k) {
            const _Float16* Tprev = (k == 2) ? h16 : slot3(k - 2);
            k_prop16x3<false><<<GRID_PROP, 256, 0, stream>>>(slot3(k - 1), Tprev,
                                                             slot3(k), off, degi, csrp);
            if ((k % 4) == 0) {
                Comb316Cfg cfg;
                const int SI[6] = {1, 2, 3, 2, 3, 3};
                for (int t = 0; t < 6; ++t) {
                    cfg.c0[t] = 0.5f * C[0][SI[t]];
                    for (int m = 0; m < 4; ++m) cfg.ck[t][m] = C[k - 3 + m][SI[t]];
                }
                k_comb316<<<GRID_C, 256, 0, stream>>>(
                    (const float4*)hacc, (const h4_t*)pool16, (h4_t*)acc2,
                    cfg, (k == 4) ? 1 : 0, (k == 16) ? 1 : 0);
            }
        }
    }

    // ---- moments: two-pass ----
    dim3 mg1(3, NGRAPH, NCHUNK);
    k_mompart<<<mg1, 256, 0, stream>>>(x, hacc, acc2, pmom);
    dim3 mg2(3, NGRAPH);
    k_momfin<<<mg2, 256, 0, stream>>>(pmom, out);
}

// Round 10
// 1567.076 us; speedup vs baseline: 1.2536x; 1.0882x over previous
//
#include <hip/hip_runtime.h>
#include <math.h>

#define NN 50000
#define NE 800000
#define NGRAPH 100
#define NPG 500
#define NB_SCAN 196
#define NCHUNK 5
#define NPC 100                        // nodes per moments chunk
#define CHAIN_ELEMS ((size_t)NN * 64)
#define CH4 ((size_t)NN * 16)          // float4 (or half4) elements per plane
#define GRID_PROP (NN / 4)             // fp32 prop: 1 node/wave, 4 waves/block
#define GRID_P163 (NN / 8)             // fp16x3 prop: 2 nodes/wave

typedef long long ll;
typedef _Float16 h4_t __attribute__((ext_vector_type(4)));
typedef _Float16 h8_t __attribute__((ext_vector_type(8)));

__device__ __forceinline__ void unpack(ll v, int& r, float& w) {
    r = (int)(v & 0xffffffffLL);
    w = __int_as_float((int)(v >> 32));
}

__device__ __forceinline__ float4 f4fma(float w, float4 v, float4 a) {
    a.x += w * v.x; a.y += w * v.y; a.z += w * v.z; a.w += w * v.w;
    return a;
}

__device__ __forceinline__ float4 h4f4(h4_t h) {
    return make_float4((float)h.x, (float)h.y, (float)h.z, (float)h.w);
}

__device__ __forceinline__ h4_t f4h4(float4 v) {
    h4_t h;
    h.x = (_Float16)v.x; h.y = (_Float16)v.y;
    h.z = (_Float16)v.z; h.w = (_Float16)v.w;
    return h;
}

// ---------------- setup kernels ----------------

__global__ void k_deg(const int* __restrict__ col, int* __restrict__ degi) {
    int e = blockIdx.x * blockDim.x + threadIdx.x;
    if (e < NE) atomicAdd(&degi[col[e]], 1);
}

__global__ void k_dh(const int* __restrict__ degi, float* __restrict__ dh) {
    int i = blockIdx.x * blockDim.x + threadIdx.x;
    if (i < NN) {
        int d = degi[i];
        dh[i] = d > 0 ? (float)(1.0 / sqrt((double)d)) : 0.0f;
    }
}

__global__ void k_bsum(const int* __restrict__ cnt, int* __restrict__ bsum) {
    __shared__ int sh[256];
    int i = blockIdx.x * 256 + threadIdx.x;
    sh[threadIdx.x] = (i < NN) ? cnt[i] : 0;
    __syncthreads();
    for (int s = 128; s > 0; s >>= 1) {
        if (threadIdx.x < s) sh[threadIdx.x] += sh[threadIdx.x + s];
        __syncthreads();
    }
    if (threadIdx.x == 0) bsum[blockIdx.x] = sh[0];
}

__global__ void k_bscan(const int* __restrict__ bsum, int* __restrict__ boff) {
    __shared__ int sh[2][256];
    int v = (threadIdx.x < NB_SCAN) ? bsum[threadIdx.x] : 0;
    int cur = 0;
    sh[0][threadIdx.x] = v;
    __syncthreads();
    for (int s = 1; s < 256; s <<= 1) {
        int val = sh[cur][threadIdx.x];
        if ((int)threadIdx.x >= s) val += sh[cur][threadIdx.x - s];
        sh[cur ^ 1][threadIdx.x] = val;
        cur ^= 1;
        __syncthreads();
    }
    if (threadIdx.x < NB_SCAN) boff[threadIdx.x] = sh[cur][threadIdx.x] - v;
}

__global__ void k_scan2(const int* __restrict__ cnt, const int* __restrict__ boff,
                        int* __restrict__ off) {
    __shared__ int sh[2][256];
    int i = blockIdx.x * 256 + threadIdx.x;
    int v = (i < NN) ? cnt[i] : 0;
    int cur = 0;
    sh[0][threadIdx.x] = v;
    __syncthreads();
    for (int s = 1; s < 256; s <<= 1) {
        int val = sh[cur][threadIdx.x];
        if ((int)threadIdx.x >= s) val += sh[cur][threadIdx.x - s];
        sh[cur ^ 1][threadIdx.x] = val;
        cur ^= 1;
        __syncthreads();
    }
    if (i < NN) off[i] = boff[blockIdx.x] + sh[cur][threadIdx.x] - v;
}

__global__ void k_fill(const int* __restrict__ row, const int* __restrict__ col,
                       const float* __restrict__ dh, const int* __restrict__ off,
                       int* __restrict__ cursor, ll* __restrict__ csrp) {
    int e = blockIdx.x * blockDim.x + threadIdx.x;
    if (e >= NE) return;
    int r = row[e], c = col[e];
    int pos = off[c] + atomicAdd(&cursor[c], 1);
    float w = dh[r] * dh[c];
    csrp[pos] = ((ll)__float_as_int(w) << 32) | (unsigned int)r;
}

// ---------------- phase-1 recurrence (R0-validated, fp32 [NN][64]) ----------
// At the measured ~101 G lines/s gather wall -- unchanged.

template <bool INIT>
__global__ __launch_bounds__(256) void k_prop(
    const float* __restrict__ Tcur, const float* __restrict__ Tprev,
    float* __restrict__ Tnext, const int* __restrict__ off,
    const int* __restrict__ degi, const ll* __restrict__ csrp) {
    int node = blockIdx.x * 4 + (threadIdx.x >> 6);
    int lane = threadIdx.x & 63;
    int eg = lane >> 4;
    int cq = lane & 15;
    int s = off[node], e = s + degi[node];
    const float* tb = Tcur + (size_t)cq * 4;
    float4 a0 = make_float4(0.f, 0.f, 0.f, 0.f);
    float4 a1 = make_float4(0.f, 0.f, 0.f, 0.f);
    float4 pv = INIT ? make_float4(0.f, 0.f, 0.f, 0.f)
                     : *(const float4*)&Tprev[(size_t)node * 64 + cq * 4];
    int i = s;
    for (; i + 8 <= e; i += 8) {
        int r0, r1; float w0, w1;
        unpack(csrp[i + eg], r0, w0);
        unpack(csrp[i + 4 + eg], r1, w1);
        float4 v0 = *(const float4*)(tb + (size_t)r0 * 64);
        float4 v1 = *(const float4*)(tb + (size_t)r1 * 64);
        a0 = f4fma(w0, v0, a0);
        a1 = f4fma(w1, v1, a1);
    }
    for (; i < e; i += 4) {
        int idx = i + eg;
        bool act = idx < e;
        int r; float w;
        unpack(csrp[act ? idx : (e - 1)], r, w);
        if (!act) w = 0.f;
        float4 v = *(const float4*)(tb + (size_t)r * 64);
        a0 = f4fma(w, v, a0);
    }
    float4 g = make_float4(a0.x + a1.x, a0.y + a1.y, a0.z + a1.z, a0.w + a1.w);
    g.x += __shfl_xor(g.x, 16); g.y += __shfl_xor(g.y, 16);
    g.z += __shfl_xor(g.z, 16); g.w += __shfl_xor(g.w, 16);
    g.x += __shfl_xor(g.x, 32); g.y += __shfl_xor(g.y, 32);
    g.z += __shfl_xor(g.z, 32); g.w += __shfl_xor(g.w, 32);
    float4 t;
    if (INIT) {
        t = make_float4(-g.x, -g.y, -g.z, -g.w);
    } else {
        t = make_float4(-2.f * g.x - pv.x, -2.f * g.y - pv.y,
                        -2.f * g.z - pv.z, -2.f * g.w - pv.w);
    }
    if (eg == 0) *(float4*)&Tnext[(size_t)node * 64 + cq * 4] = t;
}

// ---------------- phase-2 merged: 3 fp16 chains, 2 nodes per wave -----------
// lane = ns*32 + eg*8 + cq: ns = node (0..1), eg = edge slot (0..3),
// cq = 16 B chunk of the 128 B row (0..7). vs R9's 1-node/8-slot layout:
// reduce drops 3 stages -> 2 (xor 8, 16) and one wave's shuffles cover TWO
// nodes (72 -> 24 shfl/node); slot quantization improves (8-edge granule).
// fp32 accumulation; regrouping changes only fp32 rounding order.

template <bool INIT>
__global__ __launch_bounds__(256) void k_prop16x3(
    const _Float16* __restrict__ Tcur, const _Float16* __restrict__ Tprev,
    _Float16* __restrict__ Tnext, const int* __restrict__ off,
    const int* __restrict__ degi, const ll* __restrict__ csrp) {
    int wav = blockIdx.x * 4 + (threadIdx.x >> 6);
    int lane = threadIdx.x & 63;
    int ns = lane >> 5;          // node sub
    int eg = (lane >> 3) & 3;    // edge slot
    int cq = lane & 7;           // 16 B chunk
    int node = wav * 2 + ns;
    int s = off[node], e = s + degi[node];
    const _Float16* tb0 = Tcur + (size_t)cq * 8;
    const _Float16* tb1 = tb0 + CHAIN_ELEMS;
    const _Float16* tb2 = tb0 + 2 * CHAIN_ELEMS;
    float aA[3][8], aB[3][8];
#pragma unroll
    for (int p = 0; p < 3; ++p)
#pragma unroll
        for (int j = 0; j < 8; ++j) { aA[p][j] = 0.f; aB[p][j] = 0.f; }
    int i = s;
    for (; i + 8 <= e; i += 8) {
        int r0, r1; float w0, w1;
        unpack(csrp[i + eg], r0, w0);
        unpack(csrp[i + 4 + eg], r1, w1);
        size_t o0 = (size_t)r0 * 64, o1 = (size_t)r1 * 64;
        h8_t h00 = *(const h8_t*)(tb0 + o0);
        h8_t h01 = *(const h8_t*)(tb1 + o0);
        h8_t h02 = *(const h8_t*)(tb2 + o0);
        h8_t h10 = *(const h8_t*)(tb0 + o1);
        h8_t h11 = *(const h8_t*)(tb1 + o1);
        h8_t h12 = *(const h8_t*)(tb2 + o1);
#pragma unroll
        for (int j = 0; j < 8; ++j) aA[0][j] += w0 * (float)h00[j];
#pragma unroll
        for (int j = 0; j < 8; ++j) aA[1][j] += w0 * (float)h01[j];
#pragma unroll
        for (int j = 0; j < 8; ++j) aA[2][j] += w0 * (float)h02[j];
#pragma unroll
        for (int j = 0; j < 8; ++j) aB[0][j] += w1 * (float)h10[j];
#pragma unroll
        for (int j = 0; j < 8; ++j) aB[1][j] += w1 * (float)h11[j];
#pragma unroll
        for (int j = 0; j < 8; ++j) aB[2][j] += w1 * (float)h12[j];
    }
    for (; i < e; i += 4) {
        int idx = i + eg;
        bool act = idx < e;
        int r; float w;
        unpack(csrp[act ? idx : (e - 1)], r, w);
        if (!act) w = 0.f;
        size_t o = (size_t)r * 64;
        h8_t h0 = *(const h8_t*)(tb0 + o);
        h8_t h1 = *(const h8_t*)(tb1 + o);
        h8_t h2 = *(const h8_t*)(tb2 + o);
#pragma unroll
        for (int j = 0; j < 8; ++j) aA[0][j] += w * (float)h0[j];
#pragma unroll
        for (int j = 0; j < 8; ++j) aA[1][j] += w * (float)h1[j];
#pragma unroll
        for (int j = 0; j < 8; ++j) aA[2][j] += w * (float)h2[j];
    }
    float g[3][8];
#pragma unroll
    for (int p = 0; p < 3; ++p)
#pragma unroll
        for (int j = 0; j < 8; ++j) g[p][j] = aA[p][j] + aB[p][j];
    // reduce over eg (lane bits 3,4); stays within each node's half-wave
#pragma unroll
    for (int p = 0; p < 3; ++p)
#pragma unroll
        for (int j = 0; j < 8; ++j) {
            g[p][j] += __shfl_xor(g[p][j], 8);
            g[p][j] += __shfl_xor(g[p][j], 16);
        }
    if ((lane & 24) == 0) {      // eg == 0: 8 writer lanes per node
        size_t ob = (size_t)node * 64 + (size_t)cq * 8;
#pragma unroll
        for (int p = 0; p < 3; ++p) {
            size_t o = ob + (size_t)p * CHAIN_ELEMS;
            h8_t t;
            if (INIT) {
#pragma unroll
                for (int j = 0; j < 8; ++j) t[j] = (_Float16)(-g[p][j]);
            } else {
                h8_t ph = *(const h8_t*)&Tprev[o];
#pragma unroll
                for (int j = 0; j < 8; ++j)
                    t[j] = (_Float16)(-2.f * g[p][j] - (float)ph[j]);
            }
            *(h8_t*)&Tnext[o] = t;
        }
    }
}

// ---------------- combine: fp32 pool slots (phase 1) ------------------------
// On the final (doabs) pass also emits fp16 copies of planes 0..2.

struct CombCfg {
    float c0[4];
    float ck[4][8];
    int   plane[4];
};

template <int NS, int NT>
__global__ __launch_bounds__(256) void k_combine(
    const float4* __restrict__ src0, const float4* __restrict__ pool,
    float4* __restrict__ accb, _Float16* __restrict__ h16out,
    CombCfg cfg, int first, int doabs) {
    size_t v = (size_t)blockIdx.x * 256 + threadIdx.x;   // < NN*16
    float4 tv[NS];
#pragma unroll
    for (int m = 0; m < NS; ++m) tv[m] = pool[(size_t)m * CH4 + v];
    float4 s0 = first ? src0[v] : make_float4(0.f, 0.f, 0.f, 0.f);
#pragma unroll
    for (int t = 0; t < NT; ++t) {
        size_t o = (size_t)cfg.plane[t] * CH4 + v;
        float4 a;
        if (first) {
            float c = cfg.c0[t];
            a = make_float4(c * s0.x, c * s0.y, c * s0.z, c * s0.w);
        } else {
            a = accb[o];
        }
#pragma unroll
        for (int m = 0; m < NS; ++m) a = f4fma(cfg.ck[t][m], tv[m], a);
        if (doabs) a = make_float4(fabsf(a.x), fabsf(a.y), fabsf(a.z), fabsf(a.w));
        accb[o] = a;
        if (doabs && h16out && cfg.plane[t] < 3) {
            size_t eo = (size_t)cfg.plane[t] * CHAIN_ELEMS + v * 4;
            *(h4_t*)&h16out[eo] = f4h4(a);
        }
    }
}

// ---------------- merged combine: 6 targets, 3-plane fp16 slots -------------
//   t: (srcplane, acc2 plane) = (0,0) (0,1) (0,3) (1,2) (1,4) (2,5)

struct Comb316Cfg {
    float c0[6];
    float ck[6][4];
};

__global__ __launch_bounds__(256) void k_comb316(
    const float4* __restrict__ src0, const h4_t* __restrict__ pool,
    h4_t* __restrict__ accb, Comb316Cfg cfg, int first, int doabs) {
    size_t v = (size_t)blockIdx.x * 256 + threadIdx.x;   // < NN*16
    float4 tv[4][3];
#pragma unroll
    for (int m = 0; m < 4; ++m)
#pragma unroll
        for (int sp = 0; sp < 3; ++sp)
            tv[m][sp] = h4f4(pool[((size_t)m * 3 + sp) * CH4 + v]);
    float4 s0[3];
    if (first) {
#pragma unroll
        for (int sp = 0; sp < 3; ++sp) s0[sp] = src0[(size_t)sp * CH4 + v];
    }
    const int SP[6] = {0, 0, 0, 1, 1, 2};
    const int PL[6] = {0, 1, 3, 2, 4, 5};
#pragma unroll
    for (int t = 0; t < 6; ++t) {
        size_t o = (size_t)PL[t] * CH4 + v;
        float4 a;
        if (first) {
            float c = cfg.c0[t];
            float4 s = s0[SP[t]];
            a = make_float4(c * s.x, c * s.y, c * s.z, c * s.w);
        } else {
            a = h4f4(accb[o]);
        }
#pragma unroll
        for (int m = 0; m < 4; ++m) a = f4fma(cfg.ck[t][m], tv[m][SP[t]], a);
        if (doabs) a = make_float4(fabsf(a.x), fabsf(a.y), fabsf(a.z), fabsf(a.w));
        accb[o] = f4h4(a);
    }
}

// ---------------- moments: two-pass (chunked partials + finalize) -----------

__global__ void k_mompart(const float* __restrict__ x, const float* __restrict__ hacc,
                          const _Float16* __restrict__ acc2, double* __restrict__ pmom) {
    int g = blockIdx.y;
    int c = blockIdx.z;
    int col = blockIdx.x * 256 + threadIdx.x;
    if (col >= 704) return;
    int base = g * NPG + c * NPC;
    double s1 = 0, s2 = 0, s3 = 0, s4 = 0;
    if (col < 320) {
        const float* src;
        int c0;
        if (col < 64) { src = x; c0 = col; }
        else { int p = (col - 64) >> 6; src = hacc + (size_t)p * CHAIN_ELEMS; c0 = (col - 64) & 63; }
        for (int i = 0; i < NPC; ++i) {
            double v = (double)src[(size_t)(base + i) * 64 + c0];
            double v2 = v * v;
            s1 += v; s2 += v2; s3 += v2 * v; s4 += v2 * v2;
        }
    } else {
        int p = (col - 320) >> 6;
        int c0 = (col - 320) & 63;
        const _Float16* src = acc2 + (size_t)p * CHAIN_ELEMS;
        for (int i = 0; i < NPC; ++i) {
            double v = (double)(float)src[(size_t)(base + i) * 64 + c0];
            double v2 = v * v;
            s1 += v; s2 += v2; s3 += v2 * v; s4 += v2 * v2;
        }
    }
    size_t ob = (((size_t)c * NGRAPH + g) * 704 + col) * 4;
    pmom[ob + 0] = s1;
    pmom[ob + 1] = s2;
    pmom[ob + 2] = s3;
    pmom[ob + 3] = s4;
}

__global__ void k_momfin(const double* __restrict__ pmom, float* __restrict__ out) {
    int g = blockIdx.y;
    int col = blockIdx.x * 256 + threadIdx.x;
    if (col >= 704) return;
    double s1 = 0, s2 = 0, s3 = 0, s4 = 0;
    for (int c = 0; c < NCHUNK; ++c) {
        size_t ob = (((size_t)c * NGRAPH + g) * 704 + col) * 4;
        s1 += pmom[ob + 0];
        s2 += pmom[ob + 1];
        s3 += pmom[ob + 2];
        s4 += pmom[ob + 3];
    }
    double n = (double)NPG;
    double mu = s1 / n;
    double E2 = s2 / n, E3 = s3 / n, E4 = s4 / n;
    double m2 = E2 - mu * mu;
    double m3 = E3 - 3.0 * mu * E2 + 2.0 * mu * mu * mu;
    double m4 = E4 - 4.0 * mu * E3 + 6.0 * mu * mu * E2 - 3.0 * mu * mu * mu * mu;
    float m2f = (float)m2;
    float skew = 0.f, kurt = -3.f;
    if (m2f > 0.f) {
        skew = (float)(m3 / (m2 * sqrt(m2)));
        if (skew > 1e15f) skew = 0.f;
        kurt = (float)(m4 / (m2 * m2) - 3.0);
        if (kurt > 1e15f) kurt = -3.f;
    }
    size_t ob = (size_t)g * 2816 + col;
    out[ob]        = (float)mu;
    out[ob + 704]  = m2f;
    out[ob + 1408] = skew;
    out[ob + 2112] = kurt;
}

// ---------------- host ----------------

extern "C" void kernel_launch(void* const* d_in, const int* in_sizes, int n_in,
                              void* d_out, int out_size, void* d_ws, size_t ws_size,
                              hipStream_t stream) {
    const float* x = (const float*)d_in[0];
    const int* ei  = (const int*)d_in[1];
    const int* row = ei;
    const int* col = ei + NE;
    float* out = (float*)d_out;

    // Chebyshev coefficients [17][4], double precision (matches numpy)
    float C[17][4];
    {
        const int Nc = 17;
        const int scales[4] = {2, 4, 8, 16};
        for (int si = 0; si < 4; ++si) {
            double ker[17];
            for (int j = 0; j < Nc; ++j) {
                double num = cos(M_PI * (j + 0.5) / Nc);
                double b = -num;
                double v = pow(b, (double)(scales[si] / 2)) - pow(b, (double)scales[si]);
                if (v < 0) v = 0;
                ker[j] = sqrt(v);
            }
            for (int o = 0; o < Nc; ++o) {
                double acc = 0;
                for (int j = 0; j < Nc; ++j) acc += ker[j] * cos(M_PI * o * (j + 0.5) / Nc);
                C[o][si] = (float)(2.0 / Nc * acc);
            }
        }
    }

    // Workspace: union region time-shared (R9-validated):
    //   phase 1:  fp32 pool (CAD1 slots) + h16 written by final combine
    //   phase 2:  pool16 (4 slots x 3 planes) + h16 (read)
    //   moments:  pmom partials
    int*   degi; float* dh; int* off; int* cursor; int* bsum; int* boff;
    ll*    csrp; char* ub = nullptr;
    float* hacc; _Float16* acc2;
    int CAD1 = 8;
    const size_t H16B  = ((size_t)3 * CHAIN_ELEMS * 2 + 255) & ~(size_t)255;
    const size_t P16B  = ((size_t)12 * CHAIN_ELEMS * 2 + 255) & ~(size_t)255;
    const size_t PMOMB = (size_t)NCHUNK * NGRAPH * 704 * 4 * 8;
    size_t H16OFF = 0;
    for (int attempt = 0; attempt < 2; ++attempt) {
        CAD1 = (attempt == 0) ? 8 : 4;
        size_t POOLB = ((size_t)CAD1 * CHAIN_ELEMS * 4 + 255) & ~(size_t)255;
        H16OFF = (POOLB > P16B) ? POOLB : P16B;
        size_t UNB = H16OFF + H16B;
        if (PMOMB > UNB) UNB = PMOMB;
        char* p = (char*)d_ws;
        auto alloc = [&](size_t bytes) -> void* {
            void* r = (void*)p;
            p += (bytes + 255) & ~(size_t)255;
            return r;
        };
        degi   = (int*)alloc((size_t)NN * 4);
        dh     = (float*)alloc((size_t)NN * 4);
        off    = (int*)alloc((size_t)NN * 4);
        cursor = (int*)alloc((size_t)NN * 4);
        bsum   = (int*)alloc((size_t)NB_SCAN * 4);
        boff   = (int*)alloc((size_t)NB_SCAN * 4);
        csrp   = (ll*)alloc((size_t)NE * 8);
        ub     = (char*)alloc(UNB);
        hacc   = (float*)alloc((size_t)4 * CHAIN_ELEMS * 4);
        acc2   = (_Float16*)alloc((size_t)6 * CHAIN_ELEMS * 2);
        if ((size_t)(p - (char*)d_ws) <= ws_size) break;
    }
    float*    pool   = (float*)ub;                 // phase 1 slots
    _Float16* pool16 = (_Float16*)ub;              // phase 2 slots (pool dead)
    _Float16* h16    = (_Float16*)(ub + H16OFF);   // written by final combine
    double*   pmom   = (double*)ub;                // moments (all dead)

    hipMemsetAsync(degi, 0, (size_t)NN * 4, stream);
    hipMemsetAsync(cursor, 0, (size_t)NN * 4, stream);

    k_deg  <<<(NE + 255) / 256, 256, 0, stream>>>(col, degi);
    k_dh   <<<(NN + 255) / 256, 256, 0, stream>>>(degi, dh);
    k_bsum <<<NB_SCAN, 256, 0, stream>>>(degi, bsum);
    k_bscan<<<1, 256, 0, stream>>>(bsum, boff);
    k_scan2<<<NB_SCAN, 256, 0, stream>>>(degi, boff, off);
    k_fill <<<(NE + 255) / 256, 256, 0, stream>>>(row, col, dh, off, cursor, csrp);

    const int GRID_C = (int)(CH4 / 256);   // 3125

    auto slot = [&](int k) {
        return pool + (size_t)((k - 1) & (CAD1 - 1)) * CHAIN_ELEMS;
    };

    // ---- phase 1: x -> hacc planes 0..3 (|h| per scale), fp32 chain ----
    {
        const int scl[4] = {0, 1, 2, 3};
        k_prop<true><<<GRID_PROP, 256, 0, stream>>>(x, nullptr, slot(1),
                                                    off, degi, csrp);
        for (int k = 2; k <= 16; ++k) {
            const float* Tprev = (k == 2) ? x : slot(k - 2);
            k_prop<false><<<GRID_PROP, 256, 0, stream>>>(slot(k - 1), Tprev,
                                                         slot(k), off, degi, csrp);
            if ((k % CAD1) == 0) {
                CombCfg cfg;
                for (int t = 0; t < 4; ++t) {
                    int si = scl[t];
                    cfg.c0[t] = 0.5f * C[0][si];
                    cfg.plane[t] = t;
                    for (int m = 0; m < CAD1; ++m)
                        cfg.ck[t][m] = C[k - CAD1 + 1 + m][si];
                }
                int first = (k == CAD1) ? 1 : 0;
                int doabs = (k == 16) ? 1 : 0;
                _Float16* ho = doabs ? h16 : nullptr;
                if (CAD1 == 8)
                    k_combine<8, 4><<<GRID_C, 256, 0, stream>>>(
                        (const float4*)x, (const float4*)pool, (float4*)hacc,
                        ho, cfg, first, doabs);
                else
                    k_combine<4, 4><<<GRID_C, 256, 0, stream>>>(
                        (const float4*)x, (const float4*)pool, (float4*)hacc,
                        ho, cfg, first, doabs);
            }
        }
    }

    // ---- phase 2: merged 3-chain fp16 on h16 planes 0..2 -> acc2 (fp16) ----
    {
        auto slot3 = [&](int k) {
            return pool16 + (size_t)((k - 1) & 3) * 3 * CHAIN_ELEMS;
        };
        k_prop16x3<true><<<GRID_P163, 256, 0, stream>>>(h16, nullptr, slot3(1),
                                                        off, degi, csrp);
        for (int k = 2; k <= 16; ++k) {
            const _Float16* Tprev = (k == 2) ? h16 : slot3(k - 2);
            k_prop16x3<false><<<GRID_P163, 256, 0, stream>>>(slot3(k - 1), Tprev,
                                                             slot3(k), off, degi, csrp);
            if ((k % 4) == 0) {
                Comb316Cfg cfg;
                const int SI[6] = {1, 2, 3, 2, 3, 3};
                for (int t = 0; t < 6; ++t) {
                    cfg.c0[t] = 0.5f * C[0][SI[t]];
                    for (int m = 0; m < 4; ++m) cfg.ck[t][m] = C[k - 3 + m][SI[t]];
                }
                k_comb316<<<GRID_C, 256, 0, stream>>>(
                    (const float4*)hacc, (const h4_t*)pool16, (h4_t*)acc2,
                    cfg, (k == 4) ? 1 : 0, (k == 16) ? 1 : 0);
            }
        }
    }

    // ---- moments: two-pass ----
    dim3 mg1(3, NGRAPH, NCHUNK);
    k_mompart<<<mg1, 256, 0, stream>>>(x, hacc, acc2, pmom);
    dim3 mg2(3, NGRAPH);
    k_momfin<<<mg2, 256, 0, stream>>>(pmom, out);
}

// Round 11
// 1384.519 us; speedup vs baseline: 1.4189x; 1.1319x over previous
//
#include <hip/hip_runtime.h>
#include <math.h>

#define NN 50000
#define NE 800000
#define NGRAPH 100
#define NPG 500
#define NB_SCAN 196
#define NCHUNK 5
#define NPC 100                        // nodes per moments chunk
#define CHAIN_ELEMS ((size_t)NN * 64)
#define CH4 ((size_t)NN * 16)          // float4 (or half4) elements per plane
#define GRID_P163 (NN / 8)             // fp16 props: 2 nodes/wave, 4 waves/blk

typedef long long ll;
typedef _Float16 h4_t __attribute__((ext_vector_type(4)));
typedef _Float16 h8_t __attribute__((ext_vector_type(8)));

__device__ __forceinline__ void unpack(ll v, int& r, float& w) {
    r = (int)(v & 0xffffffffLL);
    w = __int_as_float((int)(v >> 32));
}

__device__ __forceinline__ float4 f4fma(float w, float4 v, float4 a) {
    a.x += w * v.x; a.y += w * v.y; a.z += w * v.z; a.w += w * v.w;
    return a;
}

__device__ __forceinline__ float4 h4f4(h4_t h) {
    return make_float4((float)h.x, (float)h.y, (float)h.z, (float)h.w);
}

__device__ __forceinline__ h4_t f4h4(float4 v) {
    h4_t h;
    h.x = (_Float16)v.x; h.y = (_Float16)v.y;
    h.z = (_Float16)v.z; h.w = (_Float16)v.w;
    return h;
}

// ---------------- setup kernels ----------------

__global__ void k_deg(const int* __restrict__ col, int* __restrict__ degi) {
    int e = blockIdx.x * blockDim.x + threadIdx.x;
    if (e < NE) atomicAdd(&degi[col[e]], 1);
}

__global__ void k_dh(const int* __restrict__ degi, float* __restrict__ dh) {
    int i = blockIdx.x * blockDim.x + threadIdx.x;
    if (i < NN) {
        int d = degi[i];
        dh[i] = d > 0 ? (float)(1.0 / sqrt((double)d)) : 0.0f;
    }
}

__global__ void k_bsum(const int* __restrict__ cnt, int* __restrict__ bsum) {
    __shared__ int sh[256];
    int i = blockIdx.x * 256 + threadIdx.x;
    sh[threadIdx.x] = (i < NN) ? cnt[i] : 0;
    __syncthreads();
    for (int s = 128; s > 0; s >>= 1) {
        if (threadIdx.x < s) sh[threadIdx.x] += sh[threadIdx.x + s];
        __syncthreads();
    }
    if (threadIdx.x == 0) bsum[blockIdx.x] = sh[0];
}

__global__ void k_bscan(const int* __restrict__ bsum, int* __restrict__ boff) {
    __shared__ int sh[2][256];
    int v = (threadIdx.x < NB_SCAN) ? bsum[threadIdx.x] : 0;
    int cur = 0;
    sh[0][threadIdx.x] = v;
    __syncthreads();
    for (int s = 1; s < 256; s <<= 1) {
        int val = sh[cur][threadIdx.x];
        if ((int)threadIdx.x >= s) val += sh[cur][threadIdx.x - s];
        sh[cur ^ 1][threadIdx.x] = val;
        cur ^= 1;
        __syncthreads();
    }
    if (threadIdx.x < NB_SCAN) boff[threadIdx.x] = sh[cur][threadIdx.x] - v;
}

__global__ void k_scan2(const int* __restrict__ cnt, const int* __restrict__ boff,
                        int* __restrict__ off) {
    __shared__ int sh[2][256];
    int i = blockIdx.x * 256 + threadIdx.x;
    int v = (i < NN) ? cnt[i] : 0;
    int cur = 0;
    sh[0][threadIdx.x] = v;
    __syncthreads();
    for (int s = 1; s < 256; s <<= 1) {
        int val = sh[cur][threadIdx.x];
        if ((int)threadIdx.x >= s) val += sh[cur][threadIdx.x - s];
        sh[cur ^ 1][threadIdx.x] = val;
        cur ^= 1;
        __syncthreads();
    }
    if (i < NN) off[i] = boff[blockIdx.x] + sh[cur][threadIdx.x] - v;
}

__global__ void k_fill(const int* __restrict__ row, const int* __restrict__ col,
                       const float* __restrict__ dh, const int* __restrict__ off,
                       int* __restrict__ cursor, ll* __restrict__ csrp) {
    int e = blockIdx.x * blockDim.x + threadIdx.x;
    if (e >= NE) return;
    int r = row[e], c = col[e];
    int pos = off[c] + atomicAdd(&cursor[c], 1);
    float w = dh[r] * dh[c];
    csrp[pos] = ((ll)__float_as_int(w) << 32) | (unsigned int)r;
}

// fp32 -> fp16 flat plane copy (x -> x16)
__global__ void k_tohalf(const float* __restrict__ src, _Float16* __restrict__ dst) {
    size_t i = ((size_t)blockIdx.x * 256 + threadIdx.x) * 4;
    float4 v = *(const float4*)&src[i];
    *(h4_t*)&dst[i] = f4h4(v);
}

// ---------------- phase-1 recurrence: single fp16 plane, 2 nodes/wave -------
// R10-validated geometry (k_prop16x3 minus two planes): lane = ns*32 + eg*8
// + cq. 2 lines/edge (vs fp32's 4) on the ~101 G lines/s gather wall.
// Weights + accumulation + reduce fp32; only the stored T_k state is fp16.

template <bool INIT>
__global__ __launch_bounds__(256) void k_prop16s(
    const _Float16* __restrict__ Tcur, const _Float16* __restrict__ Tprev,
    _Float16* __restrict__ Tnext, const int* __restrict__ off,
    const int* __restrict__ degi, const ll* __restrict__ csrp) {
    int wav = blockIdx.x * 4 + (threadIdx.x >> 6);
    int lane = threadIdx.x & 63;
    int ns = lane >> 5;
    int eg = (lane >> 3) & 3;
    int cq = lane & 7;
    int node = wav * 2 + ns;
    int s = off[node], e = s + degi[node];
    const _Float16* tb = Tcur + (size_t)cq * 8;
    float accA[8], accB[8];
#pragma unroll
    for (int j = 0; j < 8; ++j) { accA[j] = 0.f; accB[j] = 0.f; }
    int i = s;
    for (; i + 8 <= e; i += 8) {
        int r0, r1; float w0, w1;
        unpack(csrp[i + eg], r0, w0);
        unpack(csrp[i + 4 + eg], r1, w1);
        h8_t h0 = *(const h8_t*)(tb + (size_t)r0 * 64);
        h8_t h1 = *(const h8_t*)(tb + (size_t)r1 * 64);
#pragma unroll
        for (int j = 0; j < 8; ++j) accA[j] += w0 * (float)h0[j];
#pragma unroll
        for (int j = 0; j < 8; ++j) accB[j] += w1 * (float)h1[j];
    }
    for (; i < e; i += 4) {
        int idx = i + eg;
        bool act = idx < e;
        int r; float w;
        unpack(csrp[act ? idx : (e - 1)], r, w);
        if (!act) w = 0.f;
        h8_t h = *(const h8_t*)(tb + (size_t)r * 64);
#pragma unroll
        for (int j = 0; j < 8; ++j) accA[j] += w * (float)h[j];
    }
    float g[8];
#pragma unroll
    for (int j = 0; j < 8; ++j) g[j] = accA[j] + accB[j];
#pragma unroll
    for (int j = 0; j < 8; ++j) {
        g[j] += __shfl_xor(g[j], 8);
        g[j] += __shfl_xor(g[j], 16);
    }
    if ((lane & 24) == 0) {
        size_t o = (size_t)node * 64 + (size_t)cq * 8;
        h8_t t;
        if (INIT) {
#pragma unroll
            for (int j = 0; j < 8; ++j) t[j] = (_Float16)(-g[j]);
        } else {
            h8_t ph = *(const h8_t*)&Tprev[o];
#pragma unroll
            for (int j = 0; j < 8; ++j)
                t[j] = (_Float16)(-2.f * g[j] - (float)ph[j]);
        }
        *(h8_t*)&Tnext[o] = t;
    }
}

// ---------------- phase-2 merged: 3 fp16 chains, 2 nodes/wave (R10) ---------

template <bool INIT>
__global__ __launch_bounds__(256) void k_prop16x3(
    const _Float16* __restrict__ Tcur, const _Float16* __restrict__ Tprev,
    _Float16* __restrict__ Tnext, const int* __restrict__ off,
    const int* __restrict__ degi, const ll* __restrict__ csrp) {
    int wav = blockIdx.x * 4 + (threadIdx.x >> 6);
    int lane = threadIdx.x & 63;
    int ns = lane >> 5;
    int eg = (lane >> 3) & 3;
    int cq = lane & 7;
    int node = wav * 2 + ns;
    int s = off[node], e = s + degi[node];
    const _Float16* tb0 = Tcur + (size_t)cq * 8;
    const _Float16* tb1 = tb0 + CHAIN_ELEMS;
    const _Float16* tb2 = tb0 + 2 * CHAIN_ELEMS;
    float aA[3][8], aB[3][8];
#pragma unroll
    for (int p = 0; p < 3; ++p)
#pragma unroll
        for (int j = 0; j < 8; ++j) { aA[p][j] = 0.f; aB[p][j] = 0.f; }
    int i = s;
    for (; i + 8 <= e; i += 8) {
        int r0, r1; float w0, w1;
        unpack(csrp[i + eg], r0, w0);
        unpack(csrp[i + 4 + eg], r1, w1);
        size_t o0 = (size_t)r0 * 64, o1 = (size_t)r1 * 64;
        h8_t h00 = *(const h8_t*)(tb0 + o0);
        h8_t h01 = *(const h8_t*)(tb1 + o0);
        h8_t h02 = *(const h8_t*)(tb2 + o0);
        h8_t h10 = *(const h8_t*)(tb0 + o1);
        h8_t h11 = *(const h8_t*)(tb1 + o1);
        h8_t h12 = *(const h8_t*)(tb2 + o1);
#pragma unroll
        for (int j = 0; j < 8; ++j) aA[0][j] += w0 * (float)h00[j];
#pragma unroll
        for (int j = 0; j < 8; ++j) aA[1][j] += w0 * (float)h01[j];
#pragma unroll
        for (int j = 0; j < 8; ++j) aA[2][j] += w0 * (float)h02[j];
#pragma unroll
        for (int j = 0; j < 8; ++j) aB[0][j] += w1 * (float)h10[j];
#pragma unroll
        for (int j = 0; j < 8; ++j) aB[1][j] += w1 * (float)h11[j];
#pragma unroll
        for (int j = 0; j < 8; ++j) aB[2][j] += w1 * (float)h12[j];
    }
    for (; i < e; i += 4) {
        int idx = i + eg;
        bool act = idx < e;
        int r; float w;
        unpack(csrp[act ? idx : (e - 1)], r, w);
        if (!act) w = 0.f;
        size_t o = (size_t)r * 64;
        h8_t h0 = *(const h8_t*)(tb0 + o);
        h8_t h1 = *(const h8_t*)(tb1 + o);
        h8_t h2 = *(const h8_t*)(tb2 + o);
#pragma unroll
        for (int j = 0; j < 8; ++j) aA[0][j] += w * (float)h0[j];
#pragma unroll
        for (int j = 0; j < 8; ++j) aA[1][j] += w * (float)h1[j];
#pragma unroll
        for (int j = 0; j < 8; ++j) aA[2][j] += w * (float)h2[j];
    }
    float g[3][8];
#pragma unroll
    for (int p = 0; p < 3; ++p)
#pragma unroll
        for (int j = 0; j < 8; ++j) g[p][j] = aA[p][j] + aB[p][j];
#pragma unroll
    for (int p = 0; p < 3; ++p)
#pragma unroll
        for (int j = 0; j < 8; ++j) {
            g[p][j] += __shfl_xor(g[p][j], 8);
            g[p][j] += __shfl_xor(g[p][j], 16);
        }
    if ((lane & 24) == 0) {
        size_t ob = (size_t)node * 64 + (size_t)cq * 8;
#pragma unroll
        for (int p = 0; p < 3; ++p) {
            size_t o = ob + (size_t)p * CHAIN_ELEMS;
            h8_t t;
            if (INIT) {
#pragma unroll
                for (int j = 0; j < 8; ++j) t[j] = (_Float16)(-g[p][j]);
            } else {
                h8_t ph = *(const h8_t*)&Tprev[o];
#pragma unroll
                for (int j = 0; j < 8; ++j)
                    t[j] = (_Float16)(-2.f * g[p][j] - (float)ph[j]);
            }
            *(h8_t*)&Tnext[o] = t;
        }
    }
}

// ---------------- phase-1 combine: fp16 pool slots, fp32 hacc out -----------
// src0 (T0 term) stays the exact fp32 x. On the final (doabs) pass also emits
// fp16 copies of planes 0..2 for phase 2.

struct CombCfg {
    float c0[4];
    float ck[4][8];
    int   plane[4];
};

template <int NS, int NT>
__global__ __launch_bounds__(256) void k_combine16p1(
    const float4* __restrict__ src0, const h4_t* __restrict__ pool,
    float4* __restrict__ accb, _Float16* __restrict__ h16out,
    CombCfg cfg, int first, int doabs) {
    size_t v = (size_t)blockIdx.x * 256 + threadIdx.x;   // < NN*16
    float4 tv[NS];
#pragma unroll
    for (int m = 0; m < NS; ++m) tv[m] = h4f4(pool[(size_t)m * CH4 + v]);
    float4 s0 = first ? src0[v] : make_float4(0.f, 0.f, 0.f, 0.f);
#pragma unroll
    for (int t = 0; t < NT; ++t) {
        size_t o = (size_t)cfg.plane[t] * CH4 + v;
        float4 a;
        if (first) {
            float c = cfg.c0[t];
            a = make_float4(c * s0.x, c * s0.y, c * s0.z, c * s0.w);
        } else {
            a = accb[o];
        }
#pragma unroll
        for (int m = 0; m < NS; ++m) a = f4fma(cfg.ck[t][m], tv[m], a);
        if (doabs) a = make_float4(fabsf(a.x), fabsf(a.y), fabsf(a.z), fabsf(a.w));
        accb[o] = a;
        if (doabs && h16out && cfg.plane[t] < 3) {
            size_t eo = (size_t)cfg.plane[t] * CHAIN_ELEMS + v * 4;
            *(h4_t*)&h16out[eo] = f4h4(a);
        }
    }
}

// ---------------- merged combine: 6 targets, 3-plane fp16 slots -------------
//   t: (srcplane, acc2 plane) = (0,0) (0,1) (0,3) (1,2) (1,4) (2,5)

struct Comb316Cfg {
    float c0[6];
    float ck[6][4];
};

__global__ __launch_bounds__(256) void k_comb316(
    const float4* __restrict__ src0, const h4_t* __restrict__ pool,
    h4_t* __restrict__ accb, Comb316Cfg cfg, int first, int doabs) {
    size_t v = (size_t)blockIdx.x * 256 + threadIdx.x;   // < NN*16
    float4 tv[4][3];
#pragma unroll
    for (int m = 0; m < 4; ++m)
#pragma unroll
        for (int sp = 0; sp < 3; ++sp)
            tv[m][sp] = h4f4(pool[((size_t)m * 3 + sp) * CH4 + v]);
    float4 s0[3];
    if (first) {
#pragma unroll
        for (int sp = 0; sp < 3; ++sp) s0[sp] = src0[(size_t)sp * CH4 + v];
    }
    const int SP[6] = {0, 0, 0, 1, 1, 2};
    const int PL[6] = {0, 1, 3, 2, 4, 5};
#pragma unroll
    for (int t = 0; t < 6; ++t) {
        size_t o = (size_t)PL[t] * CH4 + v;
        float4 a;
        if (first) {
            float c = cfg.c0[t];
            float4 s = s0[SP[t]];
            a = make_float4(c * s.x, c * s.y, c * s.z, c * s.w);
        } else {
            a = h4f4(accb[o]);
        }
#pragma unroll
        for (int m = 0; m < 4; ++m) a = f4fma(cfg.ck[t][m], tv[m][SP[t]], a);
        if (doabs) a = make_float4(fabsf(a.x), fabsf(a.y), fabsf(a.z), fabsf(a.w));
        accb[o] = f4h4(a);
    }
}

// ---------------- moments: two-pass (chunked partials + finalize) -----------

__global__ void k_mompart(const float* __restrict__ x, const float* __restrict__ hacc,
                          const _Float16* __restrict__ acc2, double* __restrict__ pmom) {
    int g = blockIdx.y;
    int c = blockIdx.z;
    int col = blockIdx.x * 256 + threadIdx.x;
    if (col >= 704) return;
    int base = g * NPG + c * NPC;
    double s1 = 0, s2 = 0, s3 = 0, s4 = 0;
    if (col < 320) {
        const float* src;
        int c0;
        if (col < 64) { src = x; c0 = col; }
        else { int p = (col - 64) >> 6; src = hacc + (size_t)p * CHAIN_ELEMS; c0 = (col - 64) & 63; }
        for (int i = 0; i < NPC; ++i) {
            double v = (double)src[(size_t)(base + i) * 64 + c0];
            double v2 = v * v;
            s1 += v; s2 += v2; s3 += v2 * v; s4 += v2 * v2;
        }
    } else {
        int p = (col - 320) >> 6;
        int c0 = (col - 320) & 63;
        const _Float16* src = acc2 + (size_t)p * CHAIN_ELEMS;
        for (int i = 0; i < NPC; ++i) {
            double v = (double)(float)src[(size_t)(base + i) * 64 + c0];
            double v2 = v * v;
            s1 += v; s2 += v2; s3 += v2 * v; s4 += v2 * v2;
        }
    }
    size_t ob = (((size_t)c * NGRAPH + g) * 704 + col) * 4;
    pmom[ob + 0] = s1;
    pmom[ob + 1] = s2;
    pmom[ob + 2] = s3;
    pmom[ob + 3] = s4;
}

__global__ void k_momfin(const double* __restrict__ pmom, float* __restrict__ out) {
    int g = blockIdx.y;
    int col = blockIdx.x * 256 + threadIdx.x;
    if (col >= 704) return;
    double s1 = 0, s2 = 0, s3 = 0, s4 = 0;
    for (int c = 0; c < NCHUNK; ++c) {
        size_t ob = (((size_t)c * NGRAPH + g) * 704 + col) * 4;
        s1 += pmom[ob + 0];
        s2 += pmom[ob + 1];
        s3 += pmom[ob + 2];
        s4 += pmom[ob + 3];
    }
    double n = (double)NPG;
    double mu = s1 / n;
    double E2 = s2 / n, E3 = s3 / n, E4 = s4 / n;
    double m2 = E2 - mu * mu;
    double m3 = E3 - 3.0 * mu * E2 + 2.0 * mu * mu * mu;
    double m4 = E4 - 4.0 * mu * E3 + 6.0 * mu * mu * E2 - 3.0 * mu * mu * mu * mu;
    float m2f = (float)m2;
    float skew = 0.f, kurt = -3.f;
    if (m2f > 0.f) {
        skew = (float)(m3 / (m2 * sqrt(m2)));
        if (skew > 1e15f) skew = 0.f;
        kurt = (float)(m4 / (m2 * m2) - 3.0);
        if (kurt > 1e15f) kurt = -3.f;
    }
    size_t ob = (size_t)g * 2816 + col;
    out[ob]        = (float)mu;
    out[ob + 704]  = m2f;
    out[ob + 1408] = skew;
    out[ob + 2112] = kurt;
}

// ---------------- host ----------------

extern "C" void kernel_launch(void* const* d_in, const int* in_sizes, int n_in,
                              void* d_out, int out_size, void* d_ws, size_t ws_size,
                              hipStream_t stream) {
    const float* x = (const float*)d_in[0];
    const int* ei  = (const int*)d_in[1];
    const int* row = ei;
    const int* col = ei + NE;
    float* out = (float*)d_out;

    // Chebyshev coefficients [17][4], double precision (matches numpy)
    float C[17][4];
    {
        const int Nc = 17;
        const int scales[4] = {2, 4, 8, 16};
        for (int si = 0; si < 4; ++si) {
            double ker[17];
            for (int j = 0; j < Nc; ++j) {
                double num = cos(M_PI * (j + 0.5) / Nc);
                double b = -num;
                double v = pow(b, (double)(scales[si] / 2)) - pow(b, (double)scales[si]);
                if (v < 0) v = 0;
                ker[j] = sqrt(v);
            }
            for (int o = 0; o < Nc; ++o) {
                double acc = 0;
                for (int j = 0; j < Nc; ++j) acc += ker[j] * cos(M_PI * o * (j + 0.5) / Nc);
                C[o][si] = (float)(2.0 / Nc * acc);
            }
        }
    }

    // Workspace: union region time-shared:
    //   phase 1:  fp16 pool (8 slots, 51.2e6) at [0) + h16 at [H16OFF)
    //   phase 2:  pool16 (4 slots x 3 planes, 76.8e6) at [0) + h16 (read)
    //   moments:  pmom partials at [0)
    // Total ~199e6 B (< 242.5e6 proven fit).
    int*   degi; float* dh; int* off; int* cursor; int* bsum; int* boff;
    ll*    csrp; char* ub = nullptr;
    _Float16* x16; float* hacc; _Float16* acc2;
    const size_t H16B  = ((size_t)3 * CHAIN_ELEMS * 2 + 255) & ~(size_t)255;
    const size_t P1B   = ((size_t)8 * CHAIN_ELEMS * 2 + 255) & ~(size_t)255;
    const size_t P16B  = ((size_t)12 * CHAIN_ELEMS * 2 + 255) & ~(size_t)255;
    const size_t PMOMB = (size_t)NCHUNK * NGRAPH * 704 * 4 * 8;
    size_t H16OFF = (P1B > P16B) ? P1B : P16B;
    {
        size_t UNB = H16OFF + H16B;
        if (PMOMB > UNB) UNB = PMOMB;
        char* p = (char*)d_ws;
        auto alloc = [&](size_t bytes) -> void* {
            void* r = (void*)p;
            p += (bytes + 255) & ~(size_t)255;
            return r;
        };
        degi   = (int*)alloc((size_t)NN * 4);
        dh     = (float*)alloc((size_t)NN * 4);
        off    = (int*)alloc((size_t)NN * 4);
        cursor = (int*)alloc((size_t)NN * 4);
        bsum   = (int*)alloc((size_t)NB_SCAN * 4);
        boff   = (int*)alloc((size_t)NB_SCAN * 4);
        csrp   = (ll*)alloc((size_t)NE * 8);
        ub     = (char*)alloc(UNB);
        x16    = (_Float16*)alloc(CHAIN_ELEMS * 2);
        hacc   = (float*)alloc((size_t)4 * CHAIN_ELEMS * 4);
        acc2   = (_Float16*)alloc((size_t)6 * CHAIN_ELEMS * 2);
    }
    _Float16* pool1  = (_Float16*)ub;              // phase-1 slots
    _Float16* pool16 = (_Float16*)ub;              // phase-2 slots (pool1 dead)
    _Float16* h16    = (_Float16*)(ub + H16OFF);   // written by final combine
    double*   pmom   = (double*)ub;                // moments (all dead)

    hipMemsetAsync(degi, 0, (size_t)NN * 4, stream);
    hipMemsetAsync(cursor, 0, (size_t)NN * 4, stream);

    k_deg  <<<(NE + 255) / 256, 256, 0, stream>>>(col, degi);
    k_dh   <<<(NN + 255) / 256, 256, 0, stream>>>(degi, dh);
    k_bsum <<<NB_SCAN, 256, 0, stream>>>(degi, bsum);
    k_bscan<<<1, 256, 0, stream>>>(bsum, boff);
    k_scan2<<<NB_SCAN, 256, 0, stream>>>(degi, boff, off);
    k_fill <<<(NE + 255) / 256, 256, 0, stream>>>(row, col, dh, off, cursor, csrp);

    const int GRID_C = (int)(CH4 / 256);   // 3125
    k_tohalf<<<GRID_C, 256, 0, stream>>>(x, x16);

    // ---- phase 1: fp16 chain on x16 -> hacc planes 0..3 (|h| per scale) ----
    {
        auto slot1 = [&](int k) {
            return pool1 + (size_t)((k - 1) & 7) * CHAIN_ELEMS;
        };
        const int scl[4] = {0, 1, 2, 3};
        k_prop16s<true><<<GRID_P163, 256, 0, stream>>>(x16, nullptr, slot1(1),
                                                       off, degi, csrp);
        for (int k = 2; k <= 16; ++k) {
            const _Float16* Tprev = (k == 2) ? x16 : slot1(k - 2);
            k_prop16s<false><<<GRID_P163, 256, 0, stream>>>(slot1(k - 1), Tprev,
                                                            slot1(k), off, degi, csrp);
            if ((k % 8) == 0) {
                CombCfg cfg;
                for (int t = 0; t < 4; ++t) {
                    int si = scl[t];
                    cfg.c0[t] = 0.5f * C[0][si];
                    cfg.plane[t] = t;
                    for (int m = 0; m < 8; ++m)
                        cfg.ck[t][m] = C[k - 7 + m][si];
                }
                int first = (k == 8) ? 1 : 0;
                int doabs = (k == 16) ? 1 : 0;
                _Float16* ho = doabs ? h16 : nullptr;
                k_combine16p1<8, 4><<<GRID_C, 256, 0, stream>>>(
                    (const float4*)x, (const h4_t*)pool1, (float4*)hacc,
                    ho, cfg, first, doabs);
            }
        }
    }

    // ---- phase 2: merged 3-chain fp16 on h16 planes 0..2 -> acc2 (fp16) ----
    {
        auto slot3 = [&](int k) {
            return pool16 + (size_t)((k - 1) & 3) * 3 * CHAIN_ELEMS;
        };
        k_prop16x3<true><<<GRID_P163, 256, 0, stream>>>(h16, nullptr, slot3(1),
                                                        off, degi, csrp);
        for (int k = 2; k <= 16; ++k) {
            const _Float16* Tprev = (k == 2) ? h16 : slot3(k - 2);
            k_prop16x3<false><<<GRID_P163, 256, 0, stream>>>(slot3(k - 1), Tprev,
                                                             slot3(k), off, degi, csrp);
            if ((k % 4) == 0) {
                Comb316Cfg cfg;
                const int SI[6] = {1, 2, 3, 2, 3, 3};
                for (int t = 0; t < 6; ++t) {
                    cfg.c0[t] = 0.5f * C[0][SI[t]];
                    for (int m = 0; m < 4; ++m) cfg.ck[t][m] = C[k - 3 + m][SI[t]];
                }
                k_comb316<<<GRID_C, 256, 0, stream>>>(
                    (const float4*)hacc, (const h4_t*)pool16, (h4_t*)acc2,
                    cfg, (k == 4) ? 1 : 0, (k == 16) ? 1 : 0);
            }
        }
    }

    // ---- moments: two-pass ----
    dim3 mg1(3, NGRAPH, NCHUNK);
    k_mompart<<<mg1, 256, 0, stream>>>(x, hacc, acc2, pmom);
    dim3 mg2(3, NGRAPH);
    k_momfin<<<mg2, 256, 0, stream>>>(pmom, out);
}